// Round 14
// baseline (257.555 us; speedup 1.0000x reference)
//
#include <hip/hip_runtime.h>
#include <hip/hip_bf16.h>

typedef __hip_bfloat16 BF16;
typedef __attribute__((ext_vector_type(8))) short short8;
typedef __attribute__((ext_vector_type(4))) short short4v;
typedef __attribute__((ext_vector_type(4))) float f32x4;
typedef __attribute__((ext_vector_type(2))) float f32x2;

#define MFMA_B16(a,b,c) __builtin_amdgcn_mfma_f32_16x16x32_bf16((a),(b),(c),0,0,0)

#if __has_builtin(__builtin_amdgcn_exp2f)
#define EXP2F(x) __builtin_amdgcn_exp2f(x)
#else
#define EXP2F(x) __expf(0.6931471805599453f * (x))
#endif

__device__ __forceinline__ short f2bs(float f){ BF16 h = __float2bfloat16(f); return *(short*)&h; }
__device__ __forceinline__ float bs2f(short s){ BF16 h = *(BF16*)&s; return __bfloat162float(h); }

// ---------- prep: transpose+split 10 weight mats; split x into hi/lo planes ----------
struct SrcPack { const float* s[10]; };

__global__ __launch_bounds__(256) void prep_k(SrcPack p, const float* __restrict__ xsrc,
    short* __restrict__ Oh, short* __restrict__ Ol,
    short* __restrict__ xH, short* __restrict__ xL)
{
    if (blockIdx.y < 10) {
        __shared__ float s[64][65];
        const float* W = p.s[blockIdx.y];
        short* oh = Oh + (size_t)blockIdx.y * 65536;
        short* ol = Ol + (size_t)blockIdx.y * 65536;
        int tr = (blockIdx.x >> 2) * 64, tc = (blockIdx.x & 3) * 64;
        #pragma unroll
        for (int i = 0; i < 16; i++) {
            int e = threadIdx.x + i * 256;
            int r = e >> 6, c = e & 63;
            s[c][r] = W[(size_t)(tr + r) * 256 + tc + c];
        }
        __syncthreads();
        #pragma unroll
        for (int i = 0; i < 16; i++) {
            int e = threadIdx.x + i * 256;
            int c2 = e >> 6, r2 = e & 63;
            float v = s[c2][r2];
            short hi = f2bs(v);
            short lo = f2bs(v - bs2f(hi));
            size_t oi = (size_t)(tc + c2) * 256 + tr + r2;
            oh[oi] = hi;
            ol[oi] = lo;
        }
    } else {
        size_t base0 = (size_t)(blockIdx.y - 10) * 524288
                     + (size_t)blockIdx.x * 32768 + threadIdx.x * 4;
        for (int it = 0; it < 32; it++) {
            size_t idx = base0 + (size_t)it * 1024;
            float4 f = *(const float4*)&xsrc[idx];
            float v[4] = {f.x, f.y, f.z, f.w};
            short4v h, lo;
            #pragma unroll
            for (int t = 0; t < 4; t++) {
                h[t] = f2bs(v[t]);
                lo[t] = f2bs(v[t] - bs2f(h[t]));
            }
            *(short4v*)&xH[idx] = h;
            *(short4v*)&xL[idx] = lo;
        }
    }
}

// ---------- generic MFMA GEMM body, split-bf16 precision ----------
// AM: 0 = A single bf16 plane, 1 = A f32 split on the fly, 2 = A dual bf16 planes.
// OM: 0 = f32, 1 = bf16, 2 = dual planes.  BS: 1 = single-plane B (Wl unused).
// LDK = 74 shorts (37 words, odd) -> staging b128 writes ~2-way, MFMA reads conflict-free.
template<int AM, int OM, int RELU, int BS>
__device__ __forceinline__ void gemm_body(const void* __restrict__ A0,
    const void* __restrict__ Alo,
    const short* __restrict__ Wh, const short* __restrict__ Wl,
    const float* __restrict__ bias, void* __restrict__ O0, void* __restrict__ O1,
    int row0, int col0)
{
    constexpr int LDK = 74;
    __shared__ short sAh[64 * LDK];
    __shared__ short sAl[(AM == 0) ? 8 : 64 * LDK];
    __shared__ short sBh[64 * LDK];
    __shared__ short sBl[BS ? 8 : 64 * LDK];
    int tid = threadIdx.x;
    int w = tid >> 6, l = tid & 63;
    int m = l & 15, q = l >> 4;
    int sr = w * 16 + m;

    f32x4 acc[4];
    #pragma unroll
    for (int cf = 0; cf < 4; cf++) acc[cf] = (f32x4)(0.f);

    for (int kh = 0; kh < 4; kh++) {
        int kbase = kh * 64;
        #pragma unroll
        for (int i = 0; i < 2; i++) {
            int kl = q * 8 + 32 * i;
            size_t gofs = (size_t)(row0 + sr) * 256 + kbase + kl;
            if (AM == 1) {
                const float* src = (const float*)A0 + gofs;
                float4 f0 = *(const float4*)src;
                float4 f1 = *(const float4*)(src + 4);
                short8 vh, vl;
                float tmp[8] = {f0.x, f0.y, f0.z, f0.w, f1.x, f1.y, f1.z, f1.w};
                #pragma unroll
                for (int j = 0; j < 8; j++) {
                    vh[j] = f2bs(tmp[j]);
                    vl[j] = f2bs(tmp[j] - bs2f(vh[j]));
                }
                *(short8*)&sAh[sr * LDK + kl] = vh;
                *(short8*)&sAl[sr * LDK + kl] = vl;
            } else if (AM == 2) {
                *(short8*)&sAh[sr * LDK + kl] = *(const short8*)((const short*)A0 + gofs);
                *(short8*)&sAl[sr * LDK + kl] = *(const short8*)((const short*)Alo + gofs);
            } else {
                *(short8*)&sAh[sr * LDK + kl] = *(const short8*)((const short*)A0 + gofs);
            }
            size_t gofsB = (size_t)(col0 + sr) * 256 + kbase + kl;
            *(short8*)&sBh[sr * LDK + kl] = *(const short8*)(Wh + gofsB);
            if (!BS)
                *(short8*)&sBl[sr * LDK + kl] = *(const short8*)(Wl + gofsB);
        }
        __syncthreads();
        #pragma unroll
        for (int ch = 0; ch < 2; ch++) {
            int k = ch * 32 + q * 8;
            short8 ah = *(const short8*)&sAh[(w * 16 + m) * LDK + k];
            short8 al = (AM != 0) ? *(const short8*)&sAl[(w * 16 + m) * LDK + k] : ah;
            #pragma unroll
            for (int cf = 0; cf < 4; cf++) {
                short8 bh = *(const short8*)&sBh[(cf * 16 + m) * LDK + k];
                acc[cf] = MFMA_B16(ah, bh, acc[cf]);
                if (!BS) {
                    short8 bl = *(const short8*)&sBl[(cf * 16 + m) * LDK + k];
                    acc[cf] = MFMA_B16(ah, bl, acc[cf]);
                }
                if (AM != 0)
                    acc[cf] = MFMA_B16(al, bh, acc[cf]);
            }
        }
        __syncthreads();
    }
    // C/D layout: col = lane&15, row = (lane>>4)*4 + reg (m89-verified)
    #pragma unroll
    for (int cf = 0; cf < 4; cf++) {
        int col = col0 + cf * 16 + m;
        float bv = bias ? bias[col] : 0.f;
        #pragma unroll
        for (int r = 0; r < 4; r++) {
            int row = row0 + w * 16 + q * 4 + r;
            float v = acc[cf][r] + bv;
            if (RELU) v = fmaxf(v, 0.f);
            size_t oi = (size_t)row * 256 + col;
            if (OM == 0) {
                ((float*)O0)[oi] = v;
            } else if (OM == 1) {
                ((short*)O0)[oi] = f2bs(v);
            } else {
                short hi = f2bs(v);
                ((short*)O0)[oi] = hi;
                ((short*)O1)[oi] = f2bs(v - bs2f(hi));
            }
        }
    }
}

// batched-direction generic GEMM
struct GDir { const void* A0; const void* Al; const short* Wh; const short* Wl;
              const float* bias; void* O0; void* O1; };

template<int AM, int OM, int RELU, int BS>
__global__ __launch_bounds__(256) void gemm_k(GDir p0, GDir p1)
{
    GDir p = blockIdx.z ? p1 : p0;
    gemm_body<AM, OM, RELU, BS>(p.A0, p.Al, p.Wh, p.Wl, p.bias, p.O0, p.O1,
                                blockIdx.x * 64, blockIdx.y * 64);
}

// small dual GEMM (M=64): vW1 = v@mW1, vW2 = v@mW2+mb; grid (1, 8, 2)
struct G2Dir { const float* A; const short* W1h; const short* W1l;
               const short* W2h; const short* W2l; const float* b2;
               float* C1; float* C2; };

__global__ __launch_bounds__(256) void gemm2s_k(G2Dir p0, G2Dir p1)
{
    G2Dir p = blockIdx.z ? p1 : p0;
    int y = blockIdx.y;
    const short* Wh = (y < 4) ? p.W1h : p.W2h;
    const short* Wl = (y < 4) ? p.W1l : p.W2l;
    void* C = (y < 4) ? (void*)p.C1 : (void*)p.C2;
    const float* bias = (y < 4) ? nullptr : p.b2;
    gemm_body<1, 0, 0, 0>(p.A, nullptr, Wh, Wl, bias, C, nullptr, 0, (y & 3) * 64);
}

// ---------- fused dual mSA-GEMM + level-1 masked attention, 512 threads ----------
// Grid (bn*2, dchunk, dir) = 1024 blocks (r12 sweet spot). Sibling blocks
// (row-parity split) redundantly compute the full 64x64 P/Q tile (A-hi-only
// GEMM, 1 MFMA/logit), then each runs the tail for 32 interleaved rows.
// Tail = r10 lean loop: exact wave-uniform bounds, QX interleaved b64 reads,
//   P' = exp(0.4A)*(-ln2/10); w = exp2(rcp(fma(P',q,-ln2/10))) = exp(-10/(1+u)).
// h stored bf16 hi-only (r13-proven free). LDK=74 staging (conflict fix).
struct MbloDir { const short* Ah; const short* Al;
                 const short* W1h; const short* W2h;
                 const float* mb; short* Hh; int fw; };

__global__ __launch_bounds__(512) void mblo_k(MbloDir p0, MbloDir p1)
{
    __shared__ char smraw[50176] __attribute__((aligned(16)));
    short* gAh  = (short*)smraw;            // 64*74 shorts each (GEMM phase)
    short* gB1h = gAh + 4736;
    short* gB2h = gAh + 9472;
    float* aP  = (float*)smraw;             // [i*66 + l]  P' (tail phase overlay)
    float* aQX = aP + 4224;                 // [l*130 + 2j]=Q, [..+1]=X

    const float KLN = -0.06931471805599453f;   // -ln2/10

    MbloDir p = blockIdx.z ? p1 : p0;
    int tid = threadIdx.x;
    int w = tid >> 6, l = tid & 63;
    int m = l & 15, q = l >> 4;
    int rh = w >> 1;            // row strip 0..3
    int cb = (w & 1) * 2;       // col-frag base: 0 or 2
    int bn = blockIdx.x >> 1, ipar = blockIdx.x & 1;
    int row0 = bn * 64, d0 = blockIdx.y * 64;
    int srow = tid >> 3;        // staging row 0..63
    int skl  = (tid & 7) * 8;   // staging k offset

    f32x4 acc1[2], acc2[2];
    #pragma unroll
    for (int cf = 0; cf < 2; cf++) { acc1[cf] = (f32x4)(0.f); acc2[cf] = (f32x4)(0.f); }

    for (int kh = 0; kh < 4; kh++) {
        int kbase = kh * 64;
        size_t ga = (size_t)(row0 + srow) * 256 + kbase + skl;
        *(short8*)&gAh[srow * 74 + skl] = *(const short8*)(p.Ah + ga);
        size_t gb = (size_t)(d0 + srow) * 256 + kbase + skl;
        *(short8*)&gB1h[srow * 74 + skl] = *(const short8*)(p.W1h + gb);
        *(short8*)&gB2h[srow * 74 + skl] = *(const short8*)(p.W2h + gb);
        __syncthreads();
        #pragma unroll
        for (int ch = 0; ch < 2; ch++) {
            int k = ch * 32 + q * 8;
            short8 ah = *(const short8*)&gAh[(rh * 16 + m) * 74 + k];
            #pragma unroll
            for (int cf = 0; cf < 2; cf++) {
                int bofs = ((cb + cf) * 16 + m) * 74 + k;
                short8 b1 = *(const short8*)&gB1h[bofs];
                acc1[cf] = MFMA_B16(ah, b1, acc1[cf]);
                short8 b2 = *(const short8*)&gB2h[bofs];
                acc2[cf] = MFMA_B16(ah, b2, acc2[cf]);
            }
        }
        __syncthreads();   // also guards the union overwrite below
    }
    // epilogue: P' row-major (all 64 rows), Q interleaved (overlay; drained by barrier)
    #pragma unroll
    for (int cf = 0; cf < 2; cf++) {
        int col = (cb + cf) * 16 + m;
        float mbv = p.mb[d0 + col];
        #pragma unroll
        for (int r = 0; r < 4; r++) {
            int row = rh * 16 + q * 4 + r;
            aP[row * 66 + col] = __expf(0.4f * acc1[cf][r]) * KLN;
            aQX[col * 130 + 2 * row] = __expf(0.4f * (acc2[cf][r] + mbv));
        }
    }
    {   // X tile into interleaved odd slots (full hi+lo precision)
        size_t gx = (size_t)(row0 + srow) * 256 + d0 + skl;
        short8 xh = *(const short8*)(p.Ah + gx);
        short8 xl = *(const short8*)(p.Al + gx);
        #pragma unroll
        for (int t = 0; t < 8; t++)
            aQX[(skl + t) * 130 + 2 * srow + 1] = bs2f(xh[t]) + bs2f(xl[t]);
    }
    __syncthreads();
    // masked attention, exact bounds: wave w handles rows {ipar + 2*(w + 8t)}, t<4
    const float* lane_qx = &aQX[l * 130];
    #pragma unroll
    for (int t8 = 0; t8 < 4; t8++) {
        int i = ipar + 2 * (w + 8 * t8);
        float Pp = aP[i * 66 + l];
        int js = p.fw ? (i + 1) : 0;
        int je = p.fw ? 64 : i;
        float den0 = 0.f, den1 = 0.f, num0 = 0.f, num1 = 0.f;
        int j = js;
        for (; j + 4 <= je; j += 4) {
            f32x2 qx0 = *(const f32x2*)&lane_qx[2 * j];
            f32x2 qx1 = *(const f32x2*)&lane_qx[2 * j + 2];
            f32x2 qx2 = *(const f32x2*)&lane_qx[2 * j + 4];
            f32x2 qx3 = *(const f32x2*)&lane_qx[2 * j + 6];
            float w0 = EXP2F(__builtin_amdgcn_rcpf(fmaf(Pp, qx0[0], KLN)));
            float w1 = EXP2F(__builtin_amdgcn_rcpf(fmaf(Pp, qx1[0], KLN)));
            float w2 = EXP2F(__builtin_amdgcn_rcpf(fmaf(Pp, qx2[0], KLN)));
            float w3 = EXP2F(__builtin_amdgcn_rcpf(fmaf(Pp, qx3[0], KLN)));
            den0 += w0; num0 = fmaf(w0, qx0[1], num0);
            den1 += w1; num1 = fmaf(w1, qx1[1], num1);
            den0 += w2; num0 = fmaf(w2, qx2[1], num0);
            den1 += w3; num1 = fmaf(w3, qx3[1], num1);
        }
        for (; j < je; j++) {
            f32x2 qx = *(const f32x2*)&lane_qx[2 * j];
            float wgt = EXP2F(__builtin_amdgcn_rcpf(fmaf(Pp, qx[0], KLN)));
            den0 += wgt; num0 = fmaf(wgt, qx[1], num0);
        }
        float den = den0 + den1, num = num0 + num1;
        bool valid = p.fw ? (i < 63) : (i > 0);
        float out = valid ? (num * __builtin_amdgcn_rcpf(den)) : 0.f;
        p.Hh[(size_t)(row0 + i) * 256 + d0 + l] = f2bs(out);
    }
}

// ---------- fused s2t logits GEMM (single-plane W) + softmax pool ----------
struct PoolDir { const short* T1; const short* Wh; const float* bias;
                 const short* Hh; float* V; };

__global__ __launch_bounds__(256) void s2t_pool_k(PoolDir p0, PoolDir p1)
{
    __shared__ char smraw[38912] __attribute__((aligned(16)));
    short* gAh = (short*)smraw;             // 64*74
    short* gBh = gAh + 4736;
    float* aL = (float*)smraw;              // 64*68
    float* aH = aL + 4352;
    float* rm = aL + 8704;                  // 4*64
    float* rd = aL + 8960;
    float* rn = aL + 9216;

    PoolDir p = blockIdx.z ? p1 : p0;
    int tid = threadIdx.x;
    int w = tid >> 6, l = tid & 63;
    int m = l & 15, q = l >> 4;
    int sr = w * 16 + m;
    int row0 = blockIdx.x * 64, d0 = blockIdx.y * 64;

    f32x4 acc[4];
    #pragma unroll
    for (int cf = 0; cf < 4; cf++) acc[cf] = (f32x4)(0.f);

    for (int kh = 0; kh < 4; kh++) {
        int kbase = kh * 64;
        #pragma unroll
        for (int i = 0; i < 2; i++) {
            int kl = q * 8 + 32 * i;
            *(short8*)&gAh[sr * 74 + kl] =
                *(const short8*)(p.T1 + (size_t)(row0 + sr) * 256 + kbase + kl);
            *(short8*)&gBh[sr * 74 + kl] =
                *(const short8*)(p.Wh + (size_t)(d0 + sr) * 256 + kbase + kl);
        }
        __syncthreads();
        #pragma unroll
        for (int ch = 0; ch < 2; ch++) {
            int k = ch * 32 + q * 8;
            short8 ah = *(const short8*)&gAh[(w * 16 + m) * 74 + k];
            #pragma unroll
            for (int cf = 0; cf < 4; cf++) {
                short8 bh = *(const short8*)&gBh[(cf * 16 + m) * 74 + k];
                acc[cf] = MFMA_B16(ah, bh, acc[cf]);
            }
        }
        __syncthreads();
    }
    #pragma unroll
    for (int cf = 0; cf < 4; cf++) {
        int col = cf * 16 + m;
        float bv = p.bias[d0 + col];
        #pragma unroll
        for (int r = 0; r < 4; r++) {
            int row = w * 16 + q * 4 + r;
            aL[row * 68 + col] = acc[cf][r] + bv;
        }
    }
    #pragma unroll
    for (int it = 0; it < 2; it++) {
        int e = tid + it * 256;
        int j = e >> 3, d8 = (e & 7) * 8;
        short8 xh = *(const short8*)(p.Hh + (size_t)(row0 + j) * 256 + d0 + d8);
        #pragma unroll
        for (int t = 0; t < 8; t++)
            aH[j * 68 + d8 + t] = bs2f(xh[t]);
    }
    __syncthreads();
    int dl = tid & 63, rq = tid >> 6;
    float mx = -1e30f, den = 0.f, num = 0.f;
    #pragma unroll
    for (int rr = 0; rr < 16; rr++) {
        int r = rq * 16 + rr;
        float lv = aL[r * 68 + dl];
        float hv = aH[r * 68 + dl];
        if (lv > mx) {
            float sc = __expf(mx - lv);
            den *= sc; num *= sc; mx = lv;
        }
        float wgt = __expf(lv - mx);
        den += wgt; num += wgt * hv;
    }
    rm[rq * 64 + dl] = mx; rd[rq * 64 + dl] = den; rn[rq * 64 + dl] = num;
    __syncthreads();
    if (rq == 0) {
        float M = fmaxf(fmaxf(rm[dl], rm[64 + dl]), fmaxf(rm[128 + dl], rm[192 + dl]));
        float D = 0.f, Nn = 0.f;
        #pragma unroll
        for (int k = 0; k < 4; k++) {
            float sc = __expf(rm[k * 64 + dl] - M);
            D += rd[k * 64 + dl] * sc;
            Nn += rn[k * 64 + dl] * sc;
        }
        p.V[(size_t)blockIdx.x * 256 + d0 + dl] = Nn / D;
    }
}

// ---------- fused level-2 attention (row 0) + gate ----------
struct GateDir { const float* vW1; const float* vW2; const float* V;
                 const float* gW1; const float* gW2; const float* gb;
                 float* E0; int fw; };

__global__ __launch_bounds__(256) void attn2gate_k(GateDir p0, GateDir p1)
{
    GateDir p = blockIdx.z ? p1 : p0;
    __shared__ float so[256], sv[256], red[4][64];
    int b = blockIdx.x, k = threadIdx.x;
    float o = 0.f;
    if (p.fw) {
        float qv = p.vW1[(size_t)(b * 16) * 256 + k];
        float den = 0.f, num = 0.f;
        for (int j = 1; j < 16; j++) {
            float z = (qv + p.vW2[(size_t)(b * 16 + j) * 256 + k]) * 0.2f;
            float e2 = __expf(2.f * z);
            float t = 1.f - 2.f / (e2 + 1.f);
            float wgt = __expf(5.f * t);
            den += wgt; num += wgt * p.V[(size_t)(b * 16 + j) * 256 + k];
        }
        o = num / den;
    }
    so[k] = o;
    sv[k] = p.V[(size_t)(b * 16) * 256 + k];
    __syncthreads();
    int c = k & 63, ks = k >> 6;
    int gc = blockIdx.y * 64 + c;
    float acc = 0.f;
    int k0 = ks * 64;
    #pragma unroll 8
    for (int kk = 0; kk < 64; kk++) {
        int kx = k0 + kk;
        acc += so[kx] * p.gW1[(size_t)kx * 256 + gc] + sv[kx] * p.gW2[(size_t)kx * 256 + gc];
    }
    red[ks][c] = acc;
    __syncthreads();
    if (ks == 0) {
        float a = red[0][c] + red[1][c] + red[2][c] + red[3][c] + p.gb[gc];
        float G = 1.f / (1.f + __expf(-a));
        p.E0[b * 256 + gc] = G * so[gc] + (1.f - G) * sv[gc];
    }
}

// ---------- fusion: grid (64 bt, 4 dchunk, 2 dir), split-K(4x192) x 64-col ----------
struct FuseDir { const short* INh; const short* INl; const short* Hh;
                 const float* E0; const float* fW1; const float* fb1;
                 const float* fW2; const float* fb2; };

__global__ __launch_bounds__(256) void fusion_k(FuseDir p0, FuseDir p1, float* __restrict__ out)
{
    FuseDir p = blockIdx.z ? p1 : p0;
    __shared__ float cat[768];
    __shared__ float red1[4][64], red2[4][64];
    int bt = blockIdx.x, b = bt >> 4, t = bt & 15;
    int c = threadIdx.x & 63, ks = threadIdx.x >> 6;
    int gc = blockIdx.y * 64 + c;
    size_t xrow = ((size_t)b * 1024 + t) * 256;   // (b, n=0, r=t)
    cat[threadIdx.x]       = bs2f(p.INh[xrow + threadIdx.x]) + bs2f(p.INl[xrow + threadIdx.x]);
    cat[256 + threadIdx.x] = bs2f(p.Hh[xrow + threadIdx.x]);
    cat[512 + threadIdx.x] = p.E0[b * 256 + threadIdx.x];
    __syncthreads();
    float a1 = 0.f, a2 = 0.f;
    int k0 = ks * 192;
    #pragma unroll 8
    for (int kk = 0; kk < 192; kk++) {
        int k = k0 + kk;
        float cv = cat[k];
        a1 += cv * p.fW1[(size_t)k * 256 + gc];
        a2 += cv * p.fW2[(size_t)k * 256 + gc];
    }
    red1[ks][c] = a1; red2[ks][c] = a2;
    __syncthreads();
    if (ks == 0) {
        float s1 = red1[0][c] + red1[1][c] + red1[2][c] + red1[3][c] + p.fb1[gc];
        float s2 = red2[0][c] + red2[1][c] + red2[2][c] + red2[3][c] + p.fb2[gc];
        float fus = fmaxf(s1, 0.f);
        float Gf = 1.f / (1.f + __expf(-s2));
        float u = Gf * fus + (1.f - Gf) * cat[gc];
        out[((size_t)(b * 16 + t)) * 512 + (size_t)blockIdx.z * 256 + gc] = u;
    }
}

extern "C" void kernel_launch(void* const* d_in, const int* in_sizes, int n_in,
                              void* d_out, int out_size, void* d_ws, size_t ws_size,
                              hipStream_t stream)
{
    const float* x = (const float*)d_in[0];
    char* base = (char*)d_ws;
    auto alloc = [&](size_t bytes){ void* r = base; base += (bytes + 255) & ~255ULL; return r; };
    short* inH = (short*)alloc(2 * 1048576 * 2);
    short* inL = (short*)alloc(2 * 1048576 * 2);
    short* hH  = (short*)alloc(2 * 1048576 * 2);
    short* t1  = (short*)alloc(2 * 1048576 * 2);
    short* xH  = (short*)alloc(1048576 * 2);
    short* xL  = (short*)alloc(1048576 * 2);
    short* wtH = (short*)alloc(10 * 65536 * 2);
    short* wtL = (short*)alloc(10 * 65536 * 2);
    float* v   = (float*)alloc(2 * 16384 * 4);
    float* vW1 = (float*)alloc(2 * 16384 * 4);
    float* vW2 = (float*)alloc(2 * 16384 * 4);
    float* E0  = (float*)alloc(2 * 1024 * 4);

    SrcPack sp;
    const int src_idx[5] = {0, 2, 3, 5, 7};  // fcW, mW1, mW2, s2tW1, s2tW
    for (int p = 0; p < 2; p++)
        for (int i = 0; i < 5; i++)
            sp.s[p * 5 + i] = (const float*)d_in[1 + p * 16 + src_idx[i]];
    prep_k<<<dim3(16, 12), 256, 0, stream>>>(sp, x, wtH, wtL, xH, xL);

    GDir fc[2], s2t1[2];
    MbloDir mbd[2];
    PoolDir pld[2];
    G2Dir g2d[2];
    GateDir gtd[2];
    FuseDir fsd[2];
    for (int p = 0; p < 2; p++) {
        int bi = 1 + p * 16;
        const float* fcb   = (const float*)d_in[bi + 1];
        const float* mb    = (const float*)d_in[bi + 4];
        const float* s2tb1 = (const float*)d_in[bi + 6];
        const float* s2tb  = (const float*)d_in[bi + 8];
        size_t po = (size_t)p * 1048576;
        const short* W0h = wtH + (size_t)(p * 5 + 0) * 65536, *W0l = wtL + (size_t)(p * 5 + 0) * 65536;
        const short* W1h = wtH + (size_t)(p * 5 + 1) * 65536, *W1l = wtL + (size_t)(p * 5 + 1) * 65536;
        const short* W2h = wtH + (size_t)(p * 5 + 2) * 65536, *W2l = wtL + (size_t)(p * 5 + 2) * 65536;
        const short* W3h = wtH + (size_t)(p * 5 + 3) * 65536;
        const short* W4h = wtH + (size_t)(p * 5 + 4) * 65536;

        fc[p]   = { xH, xL, W0h, W0l, fcb, inH + po, inL + po };
        mbd[p]  = { inH + po, inL + po, W1h, W2h, mb, hH + po, (p == 0) };
        s2t1[p] = { hH + po, nullptr, W3h, nullptr, s2tb1, t1 + po, nullptr };
        pld[p]  = { t1 + po, W4h, s2tb, hH + po, v + p * 16384 };
        g2d[p]  = { v + p * 16384, W1h, W1l, W2h, W2l, mb, vW1 + p * 16384, vW2 + p * 16384 };
        gtd[p]  = { vW1 + p * 16384, vW2 + p * 16384, v + p * 16384,
                    (const float*)d_in[bi + 9], (const float*)d_in[bi + 10],
                    (const float*)d_in[bi + 11], E0 + p * 1024, (p == 0) };
        fsd[p]  = { inH + po, inL + po, hH + po, E0 + p * 1024,
                    (const float*)d_in[bi + 12], (const float*)d_in[bi + 13],
                    (const float*)d_in[bi + 14], (const float*)d_in[bi + 15] };
    }

    gemm_k<2, 2, 1, 0><<<dim3(64, 4, 2), 256, 0, stream>>>(fc[0], fc[1]);
    mblo_k<<<dim3(128, 4, 2), 512, 0, stream>>>(mbd[0], mbd[1]);
    gemm_k<0, 1, 1, 1><<<dim3(64, 4, 2), 256, 0, stream>>>(s2t1[0], s2t1[1]);
    s2t_pool_k<<<dim3(64, 4, 2), 256, 0, stream>>>(pld[0], pld[1]);
    gemm2s_k<<<dim3(1, 8, 2), 256, 0, stream>>>(g2d[0], g2d[1]);
    attn2gate_k<<<dim3(4, 4, 2), 256, 0, stream>>>(gtd[0], gtd[1]);
    fusion_k<<<dim3(64, 4, 2), 256, 0, stream>>>(fsd[0], fsd[1], (float*)d_out);
}

// Round 15
// 208.486 us; speedup vs baseline: 1.2354x; 1.2354x over previous
//
#include <hip/hip_runtime.h>
#include <hip/hip_bf16.h>

typedef __hip_bfloat16 BF16;
typedef __attribute__((ext_vector_type(8))) short short8;
typedef __attribute__((ext_vector_type(4))) short short4v;
typedef __attribute__((ext_vector_type(4))) float f32x4;
typedef __attribute__((ext_vector_type(2))) float f32x2;

#define MFMA_B16(a,b,c) __builtin_amdgcn_mfma_f32_16x16x32_bf16((a),(b),(c),0,0,0)

#if __has_builtin(__builtin_amdgcn_exp2f)
#define EXP2F(x) __builtin_amdgcn_exp2f(x)
#else
#define EXP2F(x) __expf(0.6931471805599453f * (x))
#endif

__device__ __forceinline__ short f2bs(float f){ BF16 h = __float2bfloat16(f); return *(short*)&h; }
__device__ __forceinline__ float bs2f(short s){ BF16 h = *(BF16*)&s; return __bfloat162float(h); }

// ---------- prep: transpose+split 10 weight mats; split x into hi/lo planes ----------
struct SrcPack { const float* s[10]; };

__global__ __launch_bounds__(256) void prep_k(SrcPack p, const float* __restrict__ xsrc,
    short* __restrict__ Oh, short* __restrict__ Ol,
    short* __restrict__ xH, short* __restrict__ xL)
{
    if (blockIdx.y < 10) {
        __shared__ float s[64][65];
        const float* W = p.s[blockIdx.y];
        short* oh = Oh + (size_t)blockIdx.y * 65536;
        short* ol = Ol + (size_t)blockIdx.y * 65536;
        int tr = (blockIdx.x >> 2) * 64, tc = (blockIdx.x & 3) * 64;
        #pragma unroll
        for (int i = 0; i < 16; i++) {
            int e = threadIdx.x + i * 256;
            int r = e >> 6, c = e & 63;
            s[c][r] = W[(size_t)(tr + r) * 256 + tc + c];
        }
        __syncthreads();
        #pragma unroll
        for (int i = 0; i < 16; i++) {
            int e = threadIdx.x + i * 256;
            int c2 = e >> 6, r2 = e & 63;
            float v = s[c2][r2];
            short hi = f2bs(v);
            short lo = f2bs(v - bs2f(hi));
            size_t oi = (size_t)(tc + c2) * 256 + tr + r2;
            oh[oi] = hi;
            ol[oi] = lo;
        }
    } else {
        size_t base0 = (size_t)(blockIdx.y - 10) * 524288
                     + (size_t)blockIdx.x * 32768 + threadIdx.x * 4;
        for (int it = 0; it < 32; it++) {
            size_t idx = base0 + (size_t)it * 1024;
            float4 f = *(const float4*)&xsrc[idx];
            float v[4] = {f.x, f.y, f.z, f.w};
            short4v h, lo;
            #pragma unroll
            for (int t = 0; t < 4; t++) {
                h[t] = f2bs(v[t]);
                lo[t] = f2bs(v[t] - bs2f(h[t]));
            }
            *(short4v*)&xH[idx] = h;
            *(short4v*)&xL[idx] = lo;
        }
    }
}

// ---------- generic MFMA GEMM body, split-bf16 precision ----------
// AM: 0 = A single bf16 plane, 1 = A f32 split on the fly, 2 = A dual bf16 planes.
// OM: 0 = f32, 1 = bf16, 2 = dual planes.  BS: 1 = single-plane B (Wl unused).
// LDK = 72 shorts: 16B-aligned short8 rows (b128 path). NOTE r14: odd-word pads
// (74) break b128 alignment and regress 1.5x — b128's 8-words/bank is the floor.
template<int AM, int OM, int RELU, int BS>
__device__ __forceinline__ void gemm_body(const void* __restrict__ A0,
    const void* __restrict__ Alo,
    const short* __restrict__ Wh, const short* __restrict__ Wl,
    const float* __restrict__ bias, void* __restrict__ O0, void* __restrict__ O1,
    int row0, int col0)
{
    constexpr int LDK = 72;
    __shared__ short sAh[64 * LDK];
    __shared__ short sAl[(AM == 0) ? 8 : 64 * LDK];
    __shared__ short sBh[64 * LDK];
    __shared__ short sBl[BS ? 8 : 64 * LDK];
    int tid = threadIdx.x;
    int w = tid >> 6, l = tid & 63;
    int m = l & 15, q = l >> 4;
    int sr = w * 16 + m;

    f32x4 acc[4];
    #pragma unroll
    for (int cf = 0; cf < 4; cf++) acc[cf] = (f32x4)(0.f);

    for (int kh = 0; kh < 4; kh++) {
        int kbase = kh * 64;
        #pragma unroll
        for (int i = 0; i < 2; i++) {
            int kl = q * 8 + 32 * i;
            size_t gofs = (size_t)(row0 + sr) * 256 + kbase + kl;
            if (AM == 1) {
                const float* src = (const float*)A0 + gofs;
                float4 f0 = *(const float4*)src;
                float4 f1 = *(const float4*)(src + 4);
                short8 vh, vl;
                float tmp[8] = {f0.x, f0.y, f0.z, f0.w, f1.x, f1.y, f1.z, f1.w};
                #pragma unroll
                for (int j = 0; j < 8; j++) {
                    vh[j] = f2bs(tmp[j]);
                    vl[j] = f2bs(tmp[j] - bs2f(vh[j]));
                }
                *(short8*)&sAh[sr * LDK + kl] = vh;
                *(short8*)&sAl[sr * LDK + kl] = vl;
            } else if (AM == 2) {
                *(short8*)&sAh[sr * LDK + kl] = *(const short8*)((const short*)A0 + gofs);
                *(short8*)&sAl[sr * LDK + kl] = *(const short8*)((const short*)Alo + gofs);
            } else {
                *(short8*)&sAh[sr * LDK + kl] = *(const short8*)((const short*)A0 + gofs);
            }
            size_t gofsB = (size_t)(col0 + sr) * 256 + kbase + kl;
            *(short8*)&sBh[sr * LDK + kl] = *(const short8*)(Wh + gofsB);
            if (!BS)
                *(short8*)&sBl[sr * LDK + kl] = *(const short8*)(Wl + gofsB);
        }
        __syncthreads();
        #pragma unroll
        for (int ch = 0; ch < 2; ch++) {
            int k = ch * 32 + q * 8;
            short8 ah = *(const short8*)&sAh[(w * 16 + m) * LDK + k];
            short8 al = (AM != 0) ? *(const short8*)&sAl[(w * 16 + m) * LDK + k] : ah;
            #pragma unroll
            for (int cf = 0; cf < 4; cf++) {
                short8 bh = *(const short8*)&sBh[(cf * 16 + m) * LDK + k];
                acc[cf] = MFMA_B16(ah, bh, acc[cf]);
                if (!BS) {
                    short8 bl = *(const short8*)&sBl[(cf * 16 + m) * LDK + k];
                    acc[cf] = MFMA_B16(ah, bl, acc[cf]);
                }
                if (AM != 0)
                    acc[cf] = MFMA_B16(al, bh, acc[cf]);
            }
        }
        __syncthreads();
    }
    // C/D layout: col = lane&15, row = (lane>>4)*4 + reg (m89-verified)
    #pragma unroll
    for (int cf = 0; cf < 4; cf++) {
        int col = col0 + cf * 16 + m;
        float bv = bias ? bias[col] : 0.f;
        #pragma unroll
        for (int r = 0; r < 4; r++) {
            int row = row0 + w * 16 + q * 4 + r;
            float v = acc[cf][r] + bv;
            if (RELU) v = fmaxf(v, 0.f);
            size_t oi = (size_t)row * 256 + col;
            if (OM == 0) {
                ((float*)O0)[oi] = v;
            } else if (OM == 1) {
                ((short*)O0)[oi] = f2bs(v);
            } else {
                short hi = f2bs(v);
                ((short*)O0)[oi] = hi;
                ((short*)O1)[oi] = f2bs(v - bs2f(hi));
            }
        }
    }
}

// batched-direction generic GEMM
struct GDir { const void* A0; const void* Al; const short* Wh; const short* Wl;
              const float* bias; void* O0; void* O1; };

template<int AM, int OM, int RELU, int BS>
__global__ __launch_bounds__(256) void gemm_k(GDir p0, GDir p1)
{
    GDir p = blockIdx.z ? p1 : p0;
    gemm_body<AM, OM, RELU, BS>(p.A0, p.Al, p.Wh, p.Wl, p.bias, p.O0, p.O1,
                                blockIdx.x * 64, blockIdx.y * 64);
}

// small dual GEMM (M=64): vW1 = v@mW1, vW2 = v@mW2+mb; grid (1, 8, 2)
struct G2Dir { const float* A; const short* W1h; const short* W1l;
               const short* W2h; const short* W2l; const float* b2;
               float* C1; float* C2; };

__global__ __launch_bounds__(256) void gemm2s_k(G2Dir p0, G2Dir p1)
{
    G2Dir p = blockIdx.z ? p1 : p0;
    int y = blockIdx.y;
    const short* Wh = (y < 4) ? p.W1h : p.W2h;
    const short* Wl = (y < 4) ? p.W1l : p.W2l;
    void* C = (y < 4) ? (void*)p.C1 : (void*)p.C2;
    const float* bias = (y < 4) ? nullptr : p.b2;
    gemm_body<1, 0, 0, 0>(p.A, nullptr, Wh, Wl, bias, C, nullptr, 0, (y & 3) * 64);
}

// ---------- fused dual mSA-GEMM + level-1 masked attention, 512 threads ----------
// Grid (bn*2, dchunk, dir) = 1024 blocks (r12 sweet spot). Sibling blocks
// (row-parity split) redundantly compute the full 64x64 P/Q tile (A-hi-only
// GEMM, 1 MFMA/logit), then each runs the tail for 32 interleaved rows.
// Tail = r10 lean loop: exact wave-uniform bounds, QX interleaved b64 reads,
//   P' = exp(0.4A)*(-ln2/10); w = exp2(rcp(fma(P',q,-ln2/10))) = exp(-10/(1+u)).
// h stored bf16 hi-only (r13-proven free). LDK=72 (16B-aligned, r14 lesson).
struct MbloDir { const short* Ah; const short* Al;
                 const short* W1h; const short* W2h;
                 const float* mb; short* Hh; int fw; };

__global__ __launch_bounds__(512) void mblo_k(MbloDir p0, MbloDir p1)
{
    __shared__ char smraw[50176] __attribute__((aligned(16)));
    short* gAh  = (short*)smraw;            // 64*72 shorts each (GEMM phase)
    short* gB1h = gAh + 4608;
    short* gB2h = gAh + 9216;
    float* aP  = (float*)smraw;             // [i*66 + l]  P' (tail phase overlay)
    float* aQX = aP + 4224;                 // [l*130 + 2j]=Q, [..+1]=X

    const float KLN = -0.06931471805599453f;   // -ln2/10

    MbloDir p = blockIdx.z ? p1 : p0;
    int tid = threadIdx.x;
    int w = tid >> 6, l = tid & 63;
    int m = l & 15, q = l >> 4;
    int rh = w >> 1;            // row strip 0..3
    int cb = (w & 1) * 2;       // col-frag base: 0 or 2
    int bn = blockIdx.x >> 1, ipar = blockIdx.x & 1;
    int row0 = bn * 64, d0 = blockIdx.y * 64;
    int srow = tid >> 3;        // staging row 0..63
    int skl  = (tid & 7) * 8;   // staging k offset

    f32x4 acc1[2], acc2[2];
    #pragma unroll
    for (int cf = 0; cf < 2; cf++) { acc1[cf] = (f32x4)(0.f); acc2[cf] = (f32x4)(0.f); }

    for (int kh = 0; kh < 4; kh++) {
        int kbase = kh * 64;
        size_t ga = (size_t)(row0 + srow) * 256 + kbase + skl;
        *(short8*)&gAh[srow * 72 + skl] = *(const short8*)(p.Ah + ga);
        size_t gb = (size_t)(d0 + srow) * 256 + kbase + skl;
        *(short8*)&gB1h[srow * 72 + skl] = *(const short8*)(p.W1h + gb);
        *(short8*)&gB2h[srow * 72 + skl] = *(const short8*)(p.W2h + gb);
        __syncthreads();
        #pragma unroll
        for (int ch = 0; ch < 2; ch++) {
            int k = ch * 32 + q * 8;
            short8 ah = *(const short8*)&gAh[(rh * 16 + m) * 72 + k];
            #pragma unroll
            for (int cf = 0; cf < 2; cf++) {
                int bofs = ((cb + cf) * 16 + m) * 72 + k;
                short8 b1 = *(const short8*)&gB1h[bofs];
                acc1[cf] = MFMA_B16(ah, b1, acc1[cf]);
                short8 b2 = *(const short8*)&gB2h[bofs];
                acc2[cf] = MFMA_B16(ah, b2, acc2[cf]);
            }
        }
        __syncthreads();   // also guards the union overwrite below
    }
    // epilogue: P' row-major (all 64 rows), Q interleaved (overlay; drained by barrier)
    #pragma unroll
    for (int cf = 0; cf < 2; cf++) {
        int col = (cb + cf) * 16 + m;
        float mbv = p.mb[d0 + col];
        #pragma unroll
        for (int r = 0; r < 4; r++) {
            int row = rh * 16 + q * 4 + r;
            aP[row * 66 + col] = __expf(0.4f * acc1[cf][r]) * KLN;
            aQX[col * 130 + 2 * row] = __expf(0.4f * (acc2[cf][r] + mbv));
        }
    }
    {   // X tile into interleaved odd slots (full hi+lo precision)
        size_t gx = (size_t)(row0 + srow) * 256 + d0 + skl;
        short8 xh = *(const short8*)(p.Ah + gx);
        short8 xl = *(const short8*)(p.Al + gx);
        #pragma unroll
        for (int t = 0; t < 8; t++)
            aQX[(skl + t) * 130 + 2 * srow + 1] = bs2f(xh[t]) + bs2f(xl[t]);
    }
    __syncthreads();
    // masked attention, exact bounds: wave w handles rows {ipar + 2*(w + 8t)}, t<4
    const float* lane_qx = &aQX[l * 130];
    #pragma unroll
    for (int t8 = 0; t8 < 4; t8++) {
        int i = ipar + 2 * (w + 8 * t8);
        float Pp = aP[i * 66 + l];
        int js = p.fw ? (i + 1) : 0;
        int je = p.fw ? 64 : i;
        float den0 = 0.f, den1 = 0.f, num0 = 0.f, num1 = 0.f;
        int j = js;
        for (; j + 4 <= je; j += 4) {
            f32x2 qx0 = *(const f32x2*)&lane_qx[2 * j];
            f32x2 qx1 = *(const f32x2*)&lane_qx[2 * j + 2];
            f32x2 qx2 = *(const f32x2*)&lane_qx[2 * j + 4];
            f32x2 qx3 = *(const f32x2*)&lane_qx[2 * j + 6];
            float w0 = EXP2F(__builtin_amdgcn_rcpf(fmaf(Pp, qx0[0], KLN)));
            float w1 = EXP2F(__builtin_amdgcn_rcpf(fmaf(Pp, qx1[0], KLN)));
            float w2 = EXP2F(__builtin_amdgcn_rcpf(fmaf(Pp, qx2[0], KLN)));
            float w3 = EXP2F(__builtin_amdgcn_rcpf(fmaf(Pp, qx3[0], KLN)));
            den0 += w0; num0 = fmaf(w0, qx0[1], num0);
            den1 += w1; num1 = fmaf(w1, qx1[1], num1);
            den0 += w2; num0 = fmaf(w2, qx2[1], num0);
            den1 += w3; num1 = fmaf(w3, qx3[1], num1);
        }
        for (; j < je; j++) {
            f32x2 qx = *(const f32x2*)&lane_qx[2 * j];
            float wgt = EXP2F(__builtin_amdgcn_rcpf(fmaf(Pp, qx[0], KLN)));
            den0 += wgt; num0 = fmaf(wgt, qx[1], num0);
        }
        float den = den0 + den1, num = num0 + num1;
        bool valid = p.fw ? (i < 63) : (i > 0);
        float out = valid ? (num * __builtin_amdgcn_rcpf(den)) : 0.f;
        p.Hh[(size_t)(row0 + i) * 256 + d0 + l] = f2bs(out);
    }
}

// ---------- fused s2t logits GEMM (single-plane W) + softmax pool ----------
struct PoolDir { const short* T1; const short* Wh; const float* bias;
                 const short* Hh; float* V; };

__global__ __launch_bounds__(256) void s2t_pool_k(PoolDir p0, PoolDir p1)
{
    __shared__ char smraw[37888] __attribute__((aligned(16)));
    short* gAh = (short*)smraw;             // 64*72
    short* gBh = gAh + 4608;
    float* aL = (float*)smraw;              // 64*68
    float* aH = aL + 4352;
    float* rm = aL + 8704;                  // 4*64
    float* rd = aL + 8960;
    float* rn = aL + 9216;

    PoolDir p = blockIdx.z ? p1 : p0;
    int tid = threadIdx.x;
    int w = tid >> 6, l = tid & 63;
    int m = l & 15, q = l >> 4;
    int sr = w * 16 + m;
    int row0 = blockIdx.x * 64, d0 = blockIdx.y * 64;

    f32x4 acc[4];
    #pragma unroll
    for (int cf = 0; cf < 4; cf++) acc[cf] = (f32x4)(0.f);

    for (int kh = 0; kh < 4; kh++) {
        int kbase = kh * 64;
        #pragma unroll
        for (int i = 0; i < 2; i++) {
            int kl = q * 8 + 32 * i;
            *(short8*)&gAh[sr * 72 + kl] =
                *(const short8*)(p.T1 + (size_t)(row0 + sr) * 256 + kbase + kl);
            *(short8*)&gBh[sr * 72 + kl] =
                *(const short8*)(p.Wh + (size_t)(d0 + sr) * 256 + kbase + kl);
        }
        __syncthreads();
        #pragma unroll
        for (int ch = 0; ch < 2; ch++) {
            int k = ch * 32 + q * 8;
            short8 ah = *(const short8*)&gAh[(w * 16 + m) * 72 + k];
            #pragma unroll
            for (int cf = 0; cf < 4; cf++) {
                short8 bh = *(const short8*)&gBh[(cf * 16 + m) * 72 + k];
                acc[cf] = MFMA_B16(ah, bh, acc[cf]);
            }
        }
        __syncthreads();
    }
    #pragma unroll
    for (int cf = 0; cf < 4; cf++) {
        int col = cf * 16 + m;
        float bv = p.bias[d0 + col];
        #pragma unroll
        for (int r = 0; r < 4; r++) {
            int row = w * 16 + q * 4 + r;
            aL[row * 68 + col] = acc[cf][r] + bv;
        }
    }
    #pragma unroll
    for (int it = 0; it < 2; it++) {
        int e = tid + it * 256;
        int j = e >> 3, d8 = (e & 7) * 8;
        short8 xh = *(const short8*)(p.Hh + (size_t)(row0 + j) * 256 + d0 + d8);
        #pragma unroll
        for (int t = 0; t < 8; t++)
            aH[j * 68 + d8 + t] = bs2f(xh[t]);
    }
    __syncthreads();
    int dl = tid & 63, rq = tid >> 6;
    float mx = -1e30f, den = 0.f, num = 0.f;
    #pragma unroll
    for (int rr = 0; rr < 16; rr++) {
        int r = rq * 16 + rr;
        float lv = aL[r * 68 + dl];
        float hv = aH[r * 68 + dl];
        if (lv > mx) {
            float sc = __expf(mx - lv);
            den *= sc; num *= sc; mx = lv;
        }
        float wgt = __expf(lv - mx);
        den += wgt; num += wgt * hv;
    }
    rm[rq * 64 + dl] = mx; rd[rq * 64 + dl] = den; rn[rq * 64 + dl] = num;
    __syncthreads();
    if (rq == 0) {
        float M = fmaxf(fmaxf(rm[dl], rm[64 + dl]), fmaxf(rm[128 + dl], rm[192 + dl]));
        float D = 0.f, Nn = 0.f;
        #pragma unroll
        for (int k = 0; k < 4; k++) {
            float sc = __expf(rm[k * 64 + dl] - M);
            D += rd[k * 64 + dl] * sc;
            Nn += rn[k * 64 + dl] * sc;
        }
        p.V[(size_t)blockIdx.x * 256 + d0 + dl] = Nn / D;
    }
}

// ---------- fused level-2 attention (row 0) + gate ----------
struct GateDir { const float* vW1; const float* vW2; const float* V;
                 const float* gW1; const float* gW2; const float* gb;
                 float* E0; int fw; };

__global__ __launch_bounds__(256) void attn2gate_k(GateDir p0, GateDir p1)
{
    GateDir p = blockIdx.z ? p1 : p0;
    __shared__ float so[256], sv[256], red[4][64];
    int b = blockIdx.x, k = threadIdx.x;
    float o = 0.f;
    if (p.fw) {
        float qv = p.vW1[(size_t)(b * 16) * 256 + k];
        float den = 0.f, num = 0.f;
        for (int j = 1; j < 16; j++) {
            float z = (qv + p.vW2[(size_t)(b * 16 + j) * 256 + k]) * 0.2f;
            float e2 = __expf(2.f * z);
            float t = 1.f - 2.f / (e2 + 1.f);
            float wgt = __expf(5.f * t);
            den += wgt; num += wgt * p.V[(size_t)(b * 16 + j) * 256 + k];
        }
        o = num / den;
    }
    so[k] = o;
    sv[k] = p.V[(size_t)(b * 16) * 256 + k];
    __syncthreads();
    int c = k & 63, ks = k >> 6;
    int gc = blockIdx.y * 64 + c;
    float acc = 0.f;
    int k0 = ks * 64;
    #pragma unroll 8
    for (int kk = 0; kk < 64; kk++) {
        int kx = k0 + kk;
        acc += so[kx] * p.gW1[(size_t)kx * 256 + gc] + sv[kx] * p.gW2[(size_t)kx * 256 + gc];
    }
    red[ks][c] = acc;
    __syncthreads();
    if (ks == 0) {
        float a = red[0][c] + red[1][c] + red[2][c] + red[3][c] + p.gb[gc];
        float G = 1.f / (1.f + __expf(-a));
        p.E0[b * 256 + gc] = G * so[gc] + (1.f - G) * sv[gc];
    }
}

// ---------- fusion: grid (64 bt, 4 dchunk, 2 dir), split-K(4x192) x 64-col ----------
struct FuseDir { const short* INh; const short* INl; const short* Hh;
                 const float* E0; const float* fW1; const float* fb1;
                 const float* fW2; const float* fb2; };

__global__ __launch_bounds__(256) void fusion_k(FuseDir p0, FuseDir p1, float* __restrict__ out)
{
    FuseDir p = blockIdx.z ? p1 : p0;
    __shared__ float cat[768];
    __shared__ float red1[4][64], red2[4][64];
    int bt = blockIdx.x, b = bt >> 4, t = bt & 15;
    int c = threadIdx.x & 63, ks = threadIdx.x >> 6;
    int gc = blockIdx.y * 64 + c;
    size_t xrow = ((size_t)b * 1024 + t) * 256;   // (b, n=0, r=t)
    cat[threadIdx.x]       = bs2f(p.INh[xrow + threadIdx.x]) + bs2f(p.INl[xrow + threadIdx.x]);
    cat[256 + threadIdx.x] = bs2f(p.Hh[xrow + threadIdx.x]);
    cat[512 + threadIdx.x] = p.E0[b * 256 + threadIdx.x];
    __syncthreads();
    float a1 = 0.f, a2 = 0.f;
    int k0 = ks * 192;
    #pragma unroll 8
    for (int kk = 0; kk < 192; kk++) {
        int k = k0 + kk;
        float cv = cat[k];
        a1 += cv * p.fW1[(size_t)k * 256 + gc];
        a2 += cv * p.fW2[(size_t)k * 256 + gc];
    }
    red1[ks][c] = a1; red2[ks][c] = a2;
    __syncthreads();
    if (ks == 0) {
        float s1 = red1[0][c] + red1[1][c] + red1[2][c] + red1[3][c] + p.fb1[gc];
        float s2 = red2[0][c] + red2[1][c] + red2[2][c] + red2[3][c] + p.fb2[gc];
        float fus = fmaxf(s1, 0.f);
        float Gf = 1.f / (1.f + __expf(-s2));
        float u = Gf * fus + (1.f - Gf) * cat[gc];
        out[((size_t)(b * 16 + t)) * 512 + (size_t)blockIdx.z * 256 + gc] = u;
    }
}

extern "C" void kernel_launch(void* const* d_in, const int* in_sizes, int n_in,
                              void* d_out, int out_size, void* d_ws, size_t ws_size,
                              hipStream_t stream)
{
    const float* x = (const float*)d_in[0];
    char* base = (char*)d_ws;
    auto alloc = [&](size_t bytes){ void* r = base; base += (bytes + 255) & ~255ULL; return r; };
    short* inH = (short*)alloc(2 * 1048576 * 2);
    short* inL = (short*)alloc(2 * 1048576 * 2);
    short* hH  = (short*)alloc(2 * 1048576 * 2);
    short* t1  = (short*)alloc(2 * 1048576 * 2);
    short* xH  = (short*)alloc(1048576 * 2);
    short* xL  = (short*)alloc(1048576 * 2);
    short* wtH = (short*)alloc(10 * 65536 * 2);
    short* wtL = (short*)alloc(10 * 65536 * 2);
    float* v   = (float*)alloc(2 * 16384 * 4);
    float* vW1 = (float*)alloc(2 * 16384 * 4);
    float* vW2 = (float*)alloc(2 * 16384 * 4);
    float* E0  = (float*)alloc(2 * 1024 * 4);

    SrcPack sp;
    const int src_idx[5] = {0, 2, 3, 5, 7};  // fcW, mW1, mW2, s2tW1, s2tW
    for (int p = 0; p < 2; p++)
        for (int i = 0; i < 5; i++)
            sp.s[p * 5 + i] = (const float*)d_in[1 + p * 16 + src_idx[i]];
    prep_k<<<dim3(16, 12), 256, 0, stream>>>(sp, x, wtH, wtL, xH, xL);

    GDir fc[2], s2t1[2];
    MbloDir mbd[2];
    PoolDir pld[2];
    G2Dir g2d[2];
    GateDir gtd[2];
    FuseDir fsd[2];
    for (int p = 0; p < 2; p++) {
        int bi = 1 + p * 16;
        const float* fcb   = (const float*)d_in[bi + 1];
        const float* mb    = (const float*)d_in[bi + 4];
        const float* s2tb1 = (const float*)d_in[bi + 6];
        const float* s2tb  = (const float*)d_in[bi + 8];
        size_t po = (size_t)p * 1048576;
        const short* W0h = wtH + (size_t)(p * 5 + 0) * 65536, *W0l = wtL + (size_t)(p * 5 + 0) * 65536;
        const short* W1h = wtH + (size_t)(p * 5 + 1) * 65536, *W1l = wtL + (size_t)(p * 5 + 1) * 65536;
        const short* W2h = wtH + (size_t)(p * 5 + 2) * 65536, *W2l = wtL + (size_t)(p * 5 + 2) * 65536;
        const short* W3h = wtH + (size_t)(p * 5 + 3) * 65536;
        const short* W4h = wtH + (size_t)(p * 5 + 4) * 65536;

        fc[p]   = { xH, xL, W0h, W0l, fcb, inH + po, inL + po };
        mbd[p]  = { inH + po, inL + po, W1h, W2h, mb, hH + po, (p == 0) };
        s2t1[p] = { hH + po, nullptr, W3h, nullptr, s2tb1, t1 + po, nullptr };
        pld[p]  = { t1 + po, W4h, s2tb, hH + po, v + p * 16384 };
        g2d[p]  = { v + p * 16384, W1h, W1l, W2h, W2l, mb, vW1 + p * 16384, vW2 + p * 16384 };
        gtd[p]  = { vW1 + p * 16384, vW2 + p * 16384, v + p * 16384,
                    (const float*)d_in[bi + 9], (const float*)d_in[bi + 10],
                    (const float*)d_in[bi + 11], E0 + p * 1024, (p == 0) };
        fsd[p]  = { inH + po, inL + po, hH + po, E0 + p * 1024,
                    (const float*)d_in[bi + 12], (const float*)d_in[bi + 13],
                    (const float*)d_in[bi + 14], (const float*)d_in[bi + 15] };
    }

    gemm_k<2, 2, 1, 0><<<dim3(64, 4, 2), 256, 0, stream>>>(fc[0], fc[1]);
    mblo_k<<<dim3(128, 4, 2), 512, 0, stream>>>(mbd[0], mbd[1]);
    gemm_k<0, 1, 1, 1><<<dim3(64, 4, 2), 256, 0, stream>>>(s2t1[0], s2t1[1]);
    s2t_pool_k<<<dim3(64, 4, 2), 256, 0, stream>>>(pld[0], pld[1]);
    gemm2s_k<<<dim3(1, 8, 2), 256, 0, stream>>>(g2d[0], g2d[1]);
    attn2gate_k<<<dim3(4, 4, 2), 256, 0, stream>>>(gtd[0], gtd[1]);
    fusion_k<<<dim3(64, 4, 2), 256, 0, stream>>>(fsd[0], fsd[1], (float*)d_out);
}

// Round 16
// 207.528 us; speedup vs baseline: 1.2411x; 1.0046x over previous
//
#include <hip/hip_runtime.h>
#include <hip/hip_bf16.h>

typedef __hip_bfloat16 BF16;
typedef __attribute__((ext_vector_type(8))) short short8;
typedef __attribute__((ext_vector_type(4))) short short4v;
typedef __attribute__((ext_vector_type(4))) float f32x4;
typedef __attribute__((ext_vector_type(2))) float f32x2;

#define MFMA_B16(a,b,c) __builtin_amdgcn_mfma_f32_16x16x32_bf16((a),(b),(c),0,0,0)

#if __has_builtin(__builtin_amdgcn_exp2f)
#define EXP2F(x) __builtin_amdgcn_exp2f(x)
#else
#define EXP2F(x) __expf(0.6931471805599453f * (x))
#endif

__device__ __forceinline__ short f2bs(float f){ BF16 h = __float2bfloat16(f); return *(short*)&h; }
__device__ __forceinline__ float bs2f(short s){ BF16 h = *(BF16*)&s; return __bfloat162float(h); }

// ---------- prep: transpose+split 10 weight mats; split x into hi/lo planes ----------
struct SrcPack { const float* s[10]; };

__global__ __launch_bounds__(256) void prep_k(SrcPack p, const float* __restrict__ xsrc,
    short* __restrict__ Oh, short* __restrict__ Ol,
    short* __restrict__ xH, short* __restrict__ xL)
{
    if (blockIdx.y < 10) {
        __shared__ float s[64][65];
        const float* W = p.s[blockIdx.y];
        short* oh = Oh + (size_t)blockIdx.y * 65536;
        short* ol = Ol + (size_t)blockIdx.y * 65536;
        int tr = (blockIdx.x >> 2) * 64, tc = (blockIdx.x & 3) * 64;
        #pragma unroll
        for (int i = 0; i < 16; i++) {
            int e = threadIdx.x + i * 256;
            int r = e >> 6, c = e & 63;
            s[c][r] = W[(size_t)(tr + r) * 256 + tc + c];
        }
        __syncthreads();
        #pragma unroll
        for (int i = 0; i < 16; i++) {
            int e = threadIdx.x + i * 256;
            int c2 = e >> 6, r2 = e & 63;
            float v = s[c2][r2];
            short hi = f2bs(v);
            short lo = f2bs(v - bs2f(hi));
            size_t oi = (size_t)(tc + c2) * 256 + tr + r2;
            oh[oi] = hi;
            ol[oi] = lo;
        }
    } else {
        size_t base0 = (size_t)(blockIdx.y - 10) * 524288
                     + (size_t)blockIdx.x * 32768 + threadIdx.x * 4;
        for (int it = 0; it < 32; it++) {
            size_t idx = base0 + (size_t)it * 1024;
            float4 f = *(const float4*)&xsrc[idx];
            float v[4] = {f.x, f.y, f.z, f.w};
            short4v h, lo;
            #pragma unroll
            for (int t = 0; t < 4; t++) {
                h[t] = f2bs(v[t]);
                lo[t] = f2bs(v[t] - bs2f(h[t]));
            }
            *(short4v*)&xH[idx] = h;
            *(short4v*)&xL[idx] = lo;
        }
    }
}

// ---------- generic MFMA GEMM body, split-bf16 precision ----------
// AM: 0 = A single bf16 plane, 1 = A f32 split on the fly, 2 = A dual bf16 planes.
// OM: 0 = f32, 1 = bf16, 2 = dual planes.  BS: 1 = single-plane B (Wl unused).
// LDK = 72 shorts: 16B-aligned short8 rows (r14 lesson: odd pads break b128).
template<int AM, int OM, int RELU, int BS>
__device__ __forceinline__ void gemm_body(const void* __restrict__ A0,
    const void* __restrict__ Alo,
    const short* __restrict__ Wh, const short* __restrict__ Wl,
    const float* __restrict__ bias, void* __restrict__ O0, void* __restrict__ O1,
    int row0, int col0)
{
    constexpr int LDK = 72;
    __shared__ short sAh[64 * LDK];
    __shared__ short sAl[(AM == 0) ? 8 : 64 * LDK];
    __shared__ short sBh[64 * LDK];
    __shared__ short sBl[BS ? 8 : 64 * LDK];
    int tid = threadIdx.x;
    int w = tid >> 6, l = tid & 63;
    int m = l & 15, q = l >> 4;
    int sr = w * 16 + m;

    f32x4 acc[4];
    #pragma unroll
    for (int cf = 0; cf < 4; cf++) acc[cf] = (f32x4)(0.f);

    for (int kh = 0; kh < 4; kh++) {
        int kbase = kh * 64;
        #pragma unroll
        for (int i = 0; i < 2; i++) {
            int kl = q * 8 + 32 * i;
            size_t gofs = (size_t)(row0 + sr) * 256 + kbase + kl;
            if (AM == 1) {
                const float* src = (const float*)A0 + gofs;
                float4 f0 = *(const float4*)src;
                float4 f1 = *(const float4*)(src + 4);
                short8 vh, vl;
                float tmp[8] = {f0.x, f0.y, f0.z, f0.w, f1.x, f1.y, f1.z, f1.w};
                #pragma unroll
                for (int j = 0; j < 8; j++) {
                    vh[j] = f2bs(tmp[j]);
                    vl[j] = f2bs(tmp[j] - bs2f(vh[j]));
                }
                *(short8*)&sAh[sr * LDK + kl] = vh;
                *(short8*)&sAl[sr * LDK + kl] = vl;
            } else if (AM == 2) {
                *(short8*)&sAh[sr * LDK + kl] = *(const short8*)((const short*)A0 + gofs);
                *(short8*)&sAl[sr * LDK + kl] = *(const short8*)((const short*)Alo + gofs);
            } else {
                *(short8*)&sAh[sr * LDK + kl] = *(const short8*)((const short*)A0 + gofs);
            }
            size_t gofsB = (size_t)(col0 + sr) * 256 + kbase + kl;
            *(short8*)&sBh[sr * LDK + kl] = *(const short8*)(Wh + gofsB);
            if (!BS)
                *(short8*)&sBl[sr * LDK + kl] = *(const short8*)(Wl + gofsB);
        }
        __syncthreads();
        #pragma unroll
        for (int ch = 0; ch < 2; ch++) {
            int k = ch * 32 + q * 8;
            short8 ah = *(const short8*)&sAh[(w * 16 + m) * LDK + k];
            short8 al = (AM != 0) ? *(const short8*)&sAl[(w * 16 + m) * LDK + k] : ah;
            #pragma unroll
            for (int cf = 0; cf < 4; cf++) {
                short8 bh = *(const short8*)&sBh[(cf * 16 + m) * LDK + k];
                acc[cf] = MFMA_B16(ah, bh, acc[cf]);
                if (!BS) {
                    short8 bl = *(const short8*)&sBl[(cf * 16 + m) * LDK + k];
                    acc[cf] = MFMA_B16(ah, bl, acc[cf]);
                }
                if (AM != 0)
                    acc[cf] = MFMA_B16(al, bh, acc[cf]);
            }
        }
        __syncthreads();
    }
    // C/D layout: col = lane&15, row = (lane>>4)*4 + reg (m89-verified)
    #pragma unroll
    for (int cf = 0; cf < 4; cf++) {
        int col = col0 + cf * 16 + m;
        float bv = bias ? bias[col] : 0.f;
        #pragma unroll
        for (int r = 0; r < 4; r++) {
            int row = row0 + w * 16 + q * 4 + r;
            float v = acc[cf][r] + bv;
            if (RELU) v = fmaxf(v, 0.f);
            size_t oi = (size_t)row * 256 + col;
            if (OM == 0) {
                ((float*)O0)[oi] = v;
            } else if (OM == 1) {
                ((short*)O0)[oi] = f2bs(v);
            } else {
                short hi = f2bs(v);
                ((short*)O0)[oi] = hi;
                ((short*)O1)[oi] = f2bs(v - bs2f(hi));
            }
        }
    }
}

// batched-direction generic GEMM
struct GDir { const void* A0; const void* Al; const short* Wh; const short* Wl;
              const float* bias; void* O0; void* O1; };

template<int AM, int OM, int RELU, int BS>
__global__ __launch_bounds__(256) void gemm_k(GDir p0, GDir p1)
{
    GDir p = blockIdx.z ? p1 : p0;
    gemm_body<AM, OM, RELU, BS>(p.A0, p.Al, p.Wh, p.Wl, p.bias, p.O0, p.O1,
                                blockIdx.x * 64, blockIdx.y * 64);
}

// small dual GEMM (M=64): vW1 = v@mW1, vW2 = v@mW2+mb; fw direction only
// (bw's attn2gate never reads vW1/vW2: o0 == 0 there). grid (1, 8, 1).
struct G2Dir { const float* A; const short* W1h; const short* W1l;
               const short* W2h; const short* W2l; const float* b2;
               float* C1; float* C2; };

__global__ __launch_bounds__(256) void gemm2s_k(G2Dir p0)
{
    G2Dir p = p0;
    int y = blockIdx.y;
    const short* Wh = (y < 4) ? p.W1h : p.W2h;
    const short* Wl = (y < 4) ? p.W1l : p.W2l;
    void* C = (y < 4) ? (void*)p.C1 : (void*)p.C2;
    const float* bias = (y < 4) ? nullptr : p.b2;
    gemm_body<1, 0, 0, 0>(p.A, nullptr, Wh, Wl, bias, C, nullptr, 0, (y & 3) * 64);
}

// ---------- fused dual mSA-GEMM + level-1 masked attention, 512 threads ----------
// Grid (bn*2, dchunk, dir) = 1024 blocks. Sibling blocks (row-parity split)
// redundantly compute the full 64x64 P/Q tile (A-hi-only GEMM), then each runs
// the tail for 32 interleaved rows. Tail LDS: QX packed as bf16 pair in one
// word [d*65 + j] (bank = (d+j)%32, 2-way free) -> 33.5 KB total -> 4 blk/CU,
// whole grid resident.  P' = exp(0.4A)*(-ln2/10);
//   w = exp2(rcp(fma(P',q,-ln2/10))) = exp(-10/(1+u)); e^5 cancels in softmax.
struct MbloDir { const short* Ah; const short* Al;
                 const short* W1h; const short* W2h;
                 const float* mb; short* Hh; int fw; };

__global__ __launch_bounds__(512) void mblo_k(MbloDir p0, MbloDir p1)
{
    __shared__ char smraw[33536] __attribute__((aligned(16)));
    short* gAh  = (short*)smraw;            // 64*72 shorts each (GEMM phase)
    short* gB1h = gAh + 4608;
    short* gB2h = gAh + 9216;
    float* aP   = (float*)smraw;            // [i*66 + l] P' (tail overlay, 16.9 KB)
    unsigned int* aQX = (unsigned int*)(smraw + 16896); // [d*65 + j]: lo=Q bf16, hi=X bf16

    const float KLN = -0.06931471805599453f;   // -ln2/10

    MbloDir p = blockIdx.z ? p1 : p0;
    int tid = threadIdx.x;
    int w = tid >> 6, l = tid & 63;
    int m = l & 15, q = l >> 4;
    int rh = w >> 1;            // row strip 0..3
    int cb = (w & 1) * 2;       // col-frag base: 0 or 2
    int bn = blockIdx.x >> 1, ipar = blockIdx.x & 1;
    int row0 = bn * 64, d0 = blockIdx.y * 64;
    int srow = tid >> 3;        // staging row 0..63
    int skl  = (tid & 7) * 8;   // staging k offset

    f32x4 acc1[2], acc2[2];
    #pragma unroll
    for (int cf = 0; cf < 2; cf++) { acc1[cf] = (f32x4)(0.f); acc2[cf] = (f32x4)(0.f); }

    for (int kh = 0; kh < 4; kh++) {
        int kbase = kh * 64;
        size_t ga = (size_t)(row0 + srow) * 256 + kbase + skl;
        *(short8*)&gAh[srow * 72 + skl] = *(const short8*)(p.Ah + ga);
        size_t gb = (size_t)(d0 + srow) * 256 + kbase + skl;
        *(short8*)&gB1h[srow * 72 + skl] = *(const short8*)(p.W1h + gb);
        *(short8*)&gB2h[srow * 72 + skl] = *(const short8*)(p.W2h + gb);
        __syncthreads();
        #pragma unroll
        for (int ch = 0; ch < 2; ch++) {
            int k = ch * 32 + q * 8;
            short8 ah = *(const short8*)&gAh[(rh * 16 + m) * 72 + k];
            #pragma unroll
            for (int cf = 0; cf < 2; cf++) {
                int bofs = ((cb + cf) * 16 + m) * 72 + k;
                short8 b1 = *(const short8*)&gB1h[bofs];
                acc1[cf] = MFMA_B16(ah, b1, acc1[cf]);
                short8 b2 = *(const short8*)&gB2h[bofs];
                acc2[cf] = MFMA_B16(ah, b2, acc2[cf]);
            }
        }
        __syncthreads();   // also guards the union overwrite below
    }
    // epilogue: P' row-major f32; Q bf16 into low half of packed QX word
    short* sQX = (short*)aQX;
    #pragma unroll
    for (int cf = 0; cf < 2; cf++) {
        int col = (cb + cf) * 16 + m;        // d index
        float mbv = p.mb[d0 + col];
        #pragma unroll
        for (int r = 0; r < 4; r++) {
            int row = rh * 16 + q * 4 + r;   // j index
            aP[row * 66 + col] = __expf(0.4f * acc1[cf][r]) * KLN;
            sQX[col * 130 + 2 * row] = f2bs(__expf(0.4f * (acc2[cf][r] + mbv)));
        }
    }
    {   // X tile (bf16 hi plane, raw copy) into high halves
        size_t gx = (size_t)(row0 + srow) * 256 + d0 + skl;
        short8 xh = *(const short8*)(p.Ah + gx);
        #pragma unroll
        for (int t = 0; t < 8; t++)
            sQX[(skl + t) * 130 + 2 * srow + 1] = xh[t];
    }
    __syncthreads();
    // masked attention, exact bounds: wave w handles rows {ipar + 2*(w + 8t)}, t<4
    const unsigned int* lane_qx = &aQX[l * 65];
    #pragma unroll
    for (int t8 = 0; t8 < 4; t8++) {
        int i = ipar + 2 * (w + 8 * t8);
        float Pp = aP[i * 66 + l];
        int js = p.fw ? (i + 1) : 0;
        int je = p.fw ? 64 : i;
        float den0 = 0.f, den1 = 0.f, num0 = 0.f, num1 = 0.f;
        int j = js;
        for (; j + 4 <= je; j += 4) {
            unsigned int u0 = lane_qx[j];
            unsigned int u1 = lane_qx[j + 1];
            unsigned int u2 = lane_qx[j + 2];
            unsigned int u3 = lane_qx[j + 3];
            float q0 = bs2f((short)(u0 & 0xffff)), x0 = bs2f((short)(u0 >> 16));
            float q1 = bs2f((short)(u1 & 0xffff)), x1 = bs2f((short)(u1 >> 16));
            float q2 = bs2f((short)(u2 & 0xffff)), x2 = bs2f((short)(u2 >> 16));
            float q3 = bs2f((short)(u3 & 0xffff)), x3 = bs2f((short)(u3 >> 16));
            float w0 = EXP2F(__builtin_amdgcn_rcpf(fmaf(Pp, q0, KLN)));
            float w1 = EXP2F(__builtin_amdgcn_rcpf(fmaf(Pp, q1, KLN)));
            float w2 = EXP2F(__builtin_amdgcn_rcpf(fmaf(Pp, q2, KLN)));
            float w3 = EXP2F(__builtin_amdgcn_rcpf(fmaf(Pp, q3, KLN)));
            den0 += w0; num0 = fmaf(w0, x0, num0);
            den1 += w1; num1 = fmaf(w1, x1, num1);
            den0 += w2; num0 = fmaf(w2, x2, num0);
            den1 += w3; num1 = fmaf(w3, x3, num1);
        }
        for (; j < je; j++) {
            unsigned int u0 = lane_qx[j];
            float q0 = bs2f((short)(u0 & 0xffff)), x0 = bs2f((short)(u0 >> 16));
            float wgt = EXP2F(__builtin_amdgcn_rcpf(fmaf(Pp, q0, KLN)));
            den0 += wgt; num0 = fmaf(wgt, x0, num0);
        }
        float den = den0 + den1, num = num0 + num1;
        bool valid = p.fw ? (i < 63) : (i > 0);
        float out = valid ? (num * __builtin_amdgcn_rcpf(den)) : 0.f;
        p.Hh[(size_t)(row0 + i) * 256 + d0 + l] = f2bs(out);
    }
}

// ---------- fused s2t logits GEMM (single-plane W) + softmax pool ----------
struct PoolDir { const short* T1; const short* Wh; const float* bias;
                 const short* Hh; float* V; };

__global__ __launch_bounds__(256) void s2t_pool_k(PoolDir p0, PoolDir p1)
{
    __shared__ char smraw[37888] __attribute__((aligned(16)));
    short* gAh = (short*)smraw;             // 64*72
    short* gBh = gAh + 4608;
    float* aL = (float*)smraw;              // 64*68
    float* aH = aL + 4352;
    float* rm = aL + 8704;                  // 4*64
    float* rd = aL + 8960;
    float* rn = aL + 9216;

    PoolDir p = blockIdx.z ? p1 : p0;
    int tid = threadIdx.x;
    int w = tid >> 6, l = tid & 63;
    int m = l & 15, q = l >> 4;
    int sr = w * 16 + m;
    int row0 = blockIdx.x * 64, d0 = blockIdx.y * 64;

    f32x4 acc[4];
    #pragma unroll
    for (int cf = 0; cf < 4; cf++) acc[cf] = (f32x4)(0.f);

    for (int kh = 0; kh < 4; kh++) {
        int kbase = kh * 64;
        #pragma unroll
        for (int i = 0; i < 2; i++) {
            int kl = q * 8 + 32 * i;
            *(short8*)&gAh[sr * 72 + kl] =
                *(const short8*)(p.T1 + (size_t)(row0 + sr) * 256 + kbase + kl);
            *(short8*)&gBh[sr * 72 + kl] =
                *(const short8*)(p.Wh + (size_t)(d0 + sr) * 256 + kbase + kl);
        }
        __syncthreads();
        #pragma unroll
        for (int ch = 0; ch < 2; ch++) {
            int k = ch * 32 + q * 8;
            short8 ah = *(const short8*)&gAh[(w * 16 + m) * 72 + k];
            #pragma unroll
            for (int cf = 0; cf < 4; cf++) {
                short8 bh = *(const short8*)&gBh[(cf * 16 + m) * 72 + k];
                acc[cf] = MFMA_B16(ah, bh, acc[cf]);
            }
        }
        __syncthreads();
    }
    #pragma unroll
    for (int cf = 0; cf < 4; cf++) {
        int col = cf * 16 + m;
        float bv = p.bias[d0 + col];
        #pragma unroll
        for (int r = 0; r < 4; r++) {
            int row = w * 16 + q * 4 + r;
            aL[row * 68 + col] = acc[cf][r] + bv;
        }
    }
    #pragma unroll
    for (int it = 0; it < 2; it++) {
        int e = tid + it * 256;
        int j = e >> 3, d8 = (e & 7) * 8;
        short8 xh = *(const short8*)(p.Hh + (size_t)(row0 + j) * 256 + d0 + d8);
        #pragma unroll
        for (int t = 0; t < 8; t++)
            aH[j * 68 + d8 + t] = bs2f(xh[t]);
    }
    __syncthreads();
    int dl = tid & 63, rq = tid >> 6;
    float mx = -1e30f, den = 0.f, num = 0.f;
    #pragma unroll
    for (int rr = 0; rr < 16; rr++) {
        int r = rq * 16 + rr;
        float lv = aL[r * 68 + dl];
        float hv = aH[r * 68 + dl];
        if (lv > mx) {
            float sc = __expf(mx - lv);
            den *= sc; num *= sc; mx = lv;
        }
        float wgt = __expf(lv - mx);
        den += wgt; num += wgt * hv;
    }
    rm[rq * 64 + dl] = mx; rd[rq * 64 + dl] = den; rn[rq * 64 + dl] = num;
    __syncthreads();
    if (rq == 0) {
        float M = fmaxf(fmaxf(rm[dl], rm[64 + dl]), fmaxf(rm[128 + dl], rm[192 + dl]));
        float D = 0.f, Nn = 0.f;
        #pragma unroll
        for (int k = 0; k < 4; k++) {
            float sc = __expf(rm[k * 64 + dl] - M);
            D += rd[k * 64 + dl] * sc;
            Nn += rn[k * 64 + dl] * sc;
        }
        p.V[(size_t)blockIdx.x * 256 + d0 + dl] = Nn / D;
    }
}

// ---------- fused level-2 attention (row 0) + gate ----------
struct GateDir { const float* vW1; const float* vW2; const float* V;
                 const float* gW1; const float* gW2; const float* gb;
                 float* E0; int fw; };

__global__ __launch_bounds__(256) void attn2gate_k(GateDir p0, GateDir p1)
{
    GateDir p = blockIdx.z ? p1 : p0;
    __shared__ float so[256], sv[256], red[4][64];
    int b = blockIdx.x, k = threadIdx.x;
    float o = 0.f;
    if (p.fw) {
        float qv = p.vW1[(size_t)(b * 16) * 256 + k];
        float den = 0.f, num = 0.f;
        for (int j = 1; j < 16; j++) {
            float z = (qv + p.vW2[(size_t)(b * 16 + j) * 256 + k]) * 0.2f;
            float e2 = __expf(2.f * z);
            float t = 1.f - 2.f / (e2 + 1.f);
            float wgt = __expf(5.f * t);
            den += wgt; num += wgt * p.V[(size_t)(b * 16 + j) * 256 + k];
        }
        o = num / den;
    }
    so[k] = o;
    sv[k] = p.V[(size_t)(b * 16) * 256 + k];
    __syncthreads();
    int c = k & 63, ks = k >> 6;
    int gc = blockIdx.y * 64 + c;
    float acc = 0.f;
    int k0 = ks * 64;
    #pragma unroll 8
    for (int kk = 0; kk < 64; kk++) {
        int kx = k0 + kk;
        acc += so[kx] * p.gW1[(size_t)kx * 256 + gc] + sv[kx] * p.gW2[(size_t)kx * 256 + gc];
    }
    red[ks][c] = acc;
    __syncthreads();
    if (ks == 0) {
        float a = red[0][c] + red[1][c] + red[2][c] + red[3][c] + p.gb[gc];
        float G = 1.f / (1.f + __expf(-a));
        p.E0[b * 256 + gc] = G * so[gc] + (1.f - G) * sv[gc];
    }
}

// ---------- fusion: grid (64 bt, 4 dchunk, 2 dir), split-K(4x192) x 64-col ----------
struct FuseDir { const short* INh; const short* INl; const short* Hh;
                 const float* E0; const float* fW1; const float* fb1;
                 const float* fW2; const float* fb2; };

__global__ __launch_bounds__(256) void fusion_k(FuseDir p0, FuseDir p1, float* __restrict__ out)
{
    FuseDir p = blockIdx.z ? p1 : p0;
    __shared__ float cat[768];
    __shared__ float red1[4][64], red2[4][64];
    int bt = blockIdx.x, b = bt >> 4, t = bt & 15;
    int c = threadIdx.x & 63, ks = threadIdx.x >> 6;
    int gc = blockIdx.y * 64 + c;
    size_t xrow = ((size_t)b * 1024 + t) * 256;   // (b, n=0, r=t)
    cat[threadIdx.x]       = bs2f(p.INh[xrow + threadIdx.x]) + bs2f(p.INl[xrow + threadIdx.x]);
    cat[256 + threadIdx.x] = bs2f(p.Hh[xrow + threadIdx.x]);
    cat[512 + threadIdx.x] = p.E0[b * 256 + threadIdx.x];
    __syncthreads();
    float a1 = 0.f, a2 = 0.f;
    int k0 = ks * 192;
    #pragma unroll 8
    for (int kk = 0; kk < 192; kk++) {
        int k = k0 + kk;
        float cv = cat[k];
        a1 += cv * p.fW1[(size_t)k * 256 + gc];
        a2 += cv * p.fW2[(size_t)k * 256 + gc];
    }
    red1[ks][c] = a1; red2[ks][c] = a2;
    __syncthreads();
    if (ks == 0) {
        float s1 = red1[0][c] + red1[1][c] + red1[2][c] + red1[3][c] + p.fb1[gc];
        float s2 = red2[0][c] + red2[1][c] + red2[2][c] + red2[3][c] + p.fb2[gc];
        float fus = fmaxf(s1, 0.f);
        float Gf = 1.f / (1.f + __expf(-s2));
        float u = Gf * fus + (1.f - Gf) * cat[gc];
        out[((size_t)(b * 16 + t)) * 512 + (size_t)blockIdx.z * 256 + gc] = u;
    }
}

extern "C" void kernel_launch(void* const* d_in, const int* in_sizes, int n_in,
                              void* d_out, int out_size, void* d_ws, size_t ws_size,
                              hipStream_t stream)
{
    const float* x = (const float*)d_in[0];
    char* base = (char*)d_ws;
    auto alloc = [&](size_t bytes){ void* r = base; base += (bytes + 255) & ~255ULL; return r; };
    short* inH = (short*)alloc(2 * 1048576 * 2);
    short* inL = (short*)alloc(2 * 1048576 * 2);
    short* hH  = (short*)alloc(2 * 1048576 * 2);
    short* t1  = (short*)alloc(2 * 1048576 * 2);
    short* xH  = (short*)alloc(1048576 * 2);
    short* xL  = (short*)alloc(1048576 * 2);
    short* wtH = (short*)alloc(10 * 65536 * 2);
    short* wtL = (short*)alloc(10 * 65536 * 2);
    float* v   = (float*)alloc(2 * 16384 * 4);
    float* vW1 = (float*)alloc(2 * 16384 * 4);
    float* vW2 = (float*)alloc(2 * 16384 * 4);
    float* E0  = (float*)alloc(2 * 1024 * 4);

    SrcPack sp;
    const int src_idx[5] = {0, 2, 3, 5, 7};  // fcW, mW1, mW2, s2tW1, s2tW
    for (int p = 0; p < 2; p++)
        for (int i = 0; i < 5; i++)
            sp.s[p * 5 + i] = (const float*)d_in[1 + p * 16 + src_idx[i]];
    prep_k<<<dim3(16, 12), 256, 0, stream>>>(sp, x, wtH, wtL, xH, xL);

    GDir fc[2], s2t1[2];
    MbloDir mbd[2];
    PoolDir pld[2];
    G2Dir g2d[2];
    GateDir gtd[2];
    FuseDir fsd[2];
    for (int p = 0; p < 2; p++) {
        int bi = 1 + p * 16;
        const float* fcb   = (const float*)d_in[bi + 1];
        const float* mb    = (const float*)d_in[bi + 4];
        const float* s2tb1 = (const float*)d_in[bi + 6];
        const float* s2tb  = (const float*)d_in[bi + 8];
        size_t po = (size_t)p * 1048576;
        const short* W0h = wtH + (size_t)(p * 5 + 0) * 65536, *W0l = wtL + (size_t)(p * 5 + 0) * 65536;
        const short* W1h = wtH + (size_t)(p * 5 + 1) * 65536, *W1l = wtL + (size_t)(p * 5 + 1) * 65536;
        const short* W2h = wtH + (size_t)(p * 5 + 2) * 65536, *W2l = wtL + (size_t)(p * 5 + 2) * 65536;
        const short* W3h = wtH + (size_t)(p * 5 + 3) * 65536;
        const short* W4h = wtH + (size_t)(p * 5 + 4) * 65536;

        fc[p]   = { xH, xL, W0h, W0l, fcb, inH + po, inL + po };
        mbd[p]  = { inH + po, inL + po, W1h, W2h, mb, hH + po, (p == 0) };
        s2t1[p] = { hH + po, nullptr, W3h, nullptr, s2tb1, t1 + po, nullptr };
        pld[p]  = { t1 + po, W4h, s2tb, hH + po, v + p * 16384 };
        g2d[p]  = { v + p * 16384, W1h, W1l, W2h, W2l, mb, vW1 + p * 16384, vW2 + p * 16384 };
        gtd[p]  = { vW1 + p * 16384, vW2 + p * 16384, v + p * 16384,
                    (const float*)d_in[bi + 9], (const float*)d_in[bi + 10],
                    (const float*)d_in[bi + 11], E0 + p * 1024, (p == 0) };
        fsd[p]  = { inH + po, inL + po, hH + po, E0 + p * 1024,
                    (const float*)d_in[bi + 12], (const float*)d_in[bi + 13],
                    (const float*)d_in[bi + 14], (const float*)d_in[bi + 15] };
    }

    gemm_k<2, 2, 1, 0><<<dim3(64, 4, 2), 256, 0, stream>>>(fc[0], fc[1]);
    mblo_k<<<dim3(128, 4, 2), 512, 0, stream>>>(mbd[0], mbd[1]);
    gemm_k<0, 1, 1, 1><<<dim3(64, 4, 2), 256, 0, stream>>>(s2t1[0], s2t1[1]);
    s2t_pool_k<<<dim3(64, 4, 2), 256, 0, stream>>>(pld[0], pld[1]);
    gemm2s_k<<<dim3(1, 8, 1), 256, 0, stream>>>(g2d[0]);   // fw only: bw never reads vW1/vW2
    attn2gate_k<<<dim3(4, 4, 2), 256, 0, stream>>>(gtd[0], gtd[1]);
    fusion_k<<<dim3(64, 4, 2), 256, 0, stream>>>(fsd[0], fsd[1], (float*)d_out);
}

// Round 17
// 206.082 us; speedup vs baseline: 1.2498x; 1.0070x over previous
//
#include <hip/hip_runtime.h>
#include <hip/hip_bf16.h>

typedef __hip_bfloat16 BF16;
typedef __attribute__((ext_vector_type(8))) short short8;
typedef __attribute__((ext_vector_type(4))) float f32x4;

#define MFMA_B16(a,b,c) __builtin_amdgcn_mfma_f32_16x16x32_bf16((a),(b),(c),0,0,0)

#if __has_builtin(__builtin_amdgcn_exp2f)
#define EXP2F(x) __builtin_amdgcn_exp2f(x)
#else
#define EXP2F(x) __expf(0.6931471805599453f * (x))
#endif

__device__ __forceinline__ short f2bs(float f){ BF16 h = __float2bfloat16(f); return *(short*)&h; }
__device__ __forceinline__ float bs2f(short s){ BF16 h = *(BF16*)&s; return __bfloat162float(h); }

// ---------- prep: transpose+split 10 f32 weight mats to n-major bf16 hi/lo ----------
struct SrcPack { const float* s[10]; };

__global__ __launch_bounds__(256) void prep_k(SrcPack p, short* __restrict__ Oh,
                                              short* __restrict__ Ol)
{
    __shared__ float s[64][65];
    const float* W = p.s[blockIdx.y];
    short* oh = Oh + (size_t)blockIdx.y * 65536;
    short* ol = Ol + (size_t)blockIdx.y * 65536;
    int tr = (blockIdx.x >> 2) * 64, tc = (blockIdx.x & 3) * 64;
    #pragma unroll
    for (int i = 0; i < 16; i++) {
        int e = threadIdx.x + i * 256;
        int r = e >> 6, c = e & 63;
        s[c][r] = W[(size_t)(tr + r) * 256 + tc + c];
    }
    __syncthreads();
    #pragma unroll
    for (int i = 0; i < 16; i++) {
        int e = threadIdx.x + i * 256;
        int c2 = e >> 6, r2 = e & 63;
        float v = s[c2][r2];
        short hi = f2bs(v);
        short lo = f2bs(v - bs2f(hi));
        size_t oi = (size_t)(tc + c2) * 256 + tr + r2;
        oh[oi] = hi;
        ol[oi] = lo;
    }
}

// ---------- generic MFMA GEMM body, split-bf16 precision ----------
// AM: 0 = A single bf16 plane, 1 = A f32 split on the fly, 2 = A dual bf16 planes.
// OM: 0 = f32, 1 = bf16, 2 = dual planes.  BS: 1 = single-plane B (Wl unused).
// LDK = 72 shorts: 16B-aligned short8 rows (r14 lesson: odd pads break b128).
template<int AM, int OM, int RELU, int BS>
__device__ __forceinline__ void gemm_body(const void* __restrict__ A0,
    const void* __restrict__ Alo,
    const short* __restrict__ Wh, const short* __restrict__ Wl,
    const float* __restrict__ bias, void* __restrict__ O0, void* __restrict__ O1,
    int row0, int col0)
{
    constexpr int LDK = 72;
    __shared__ short sAh[64 * LDK];
    __shared__ short sAl[(AM == 0) ? 8 : 64 * LDK];
    __shared__ short sBh[64 * LDK];
    __shared__ short sBl[BS ? 8 : 64 * LDK];
    int tid = threadIdx.x;
    int w = tid >> 6, l = tid & 63;
    int m = l & 15, q = l >> 4;
    int sr = w * 16 + m;

    f32x4 acc[4];
    #pragma unroll
    for (int cf = 0; cf < 4; cf++) acc[cf] = (f32x4)(0.f);

    for (int kh = 0; kh < 4; kh++) {
        int kbase = kh * 64;
        #pragma unroll
        for (int i = 0; i < 2; i++) {
            int kl = q * 8 + 32 * i;
            size_t gofs = (size_t)(row0 + sr) * 256 + kbase + kl;
            if (AM == 1) {
                const float* src = (const float*)A0 + gofs;
                float4 f0 = *(const float4*)src;
                float4 f1 = *(const float4*)(src + 4);
                short8 vh, vl;
                float tmp[8] = {f0.x, f0.y, f0.z, f0.w, f1.x, f1.y, f1.z, f1.w};
                #pragma unroll
                for (int j = 0; j < 8; j++) {
                    vh[j] = f2bs(tmp[j]);
                    vl[j] = f2bs(tmp[j] - bs2f(vh[j]));
                }
                *(short8*)&sAh[sr * LDK + kl] = vh;
                *(short8*)&sAl[sr * LDK + kl] = vl;
            } else if (AM == 2) {
                *(short8*)&sAh[sr * LDK + kl] = *(const short8*)((const short*)A0 + gofs);
                *(short8*)&sAl[sr * LDK + kl] = *(const short8*)((const short*)Alo + gofs);
            } else {
                *(short8*)&sAh[sr * LDK + kl] = *(const short8*)((const short*)A0 + gofs);
            }
            size_t gofsB = (size_t)(col0 + sr) * 256 + kbase + kl;
            *(short8*)&sBh[sr * LDK + kl] = *(const short8*)(Wh + gofsB);
            if (!BS)
                *(short8*)&sBl[sr * LDK + kl] = *(const short8*)(Wl + gofsB);
        }
        __syncthreads();
        #pragma unroll
        for (int ch = 0; ch < 2; ch++) {
            int k = ch * 32 + q * 8;
            short8 ah = *(const short8*)&sAh[(w * 16 + m) * LDK + k];
            short8 al = (AM != 0) ? *(const short8*)&sAl[(w * 16 + m) * LDK + k] : ah;
            #pragma unroll
            for (int cf = 0; cf < 4; cf++) {
                short8 bh = *(const short8*)&sBh[(cf * 16 + m) * LDK + k];
                acc[cf] = MFMA_B16(ah, bh, acc[cf]);
                if (!BS) {
                    short8 bl = *(const short8*)&sBl[(cf * 16 + m) * LDK + k];
                    acc[cf] = MFMA_B16(ah, bl, acc[cf]);
                }
                if (AM != 0)
                    acc[cf] = MFMA_B16(al, bh, acc[cf]);
            }
        }
        __syncthreads();
    }
    // C/D layout: col = lane&15, row = (lane>>4)*4 + reg (m89-verified)
    #pragma unroll
    for (int cf = 0; cf < 4; cf++) {
        int col = col0 + cf * 16 + m;
        float bv = bias ? bias[col] : 0.f;
        #pragma unroll
        for (int r = 0; r < 4; r++) {
            int row = row0 + w * 16 + q * 4 + r;
            float v = acc[cf][r] + bv;
            if (RELU) v = fmaxf(v, 0.f);
            size_t oi = (size_t)row * 256 + col;
            if (OM == 0) {
                ((float*)O0)[oi] = v;
            } else if (OM == 1) {
                ((short*)O0)[oi] = f2bs(v);
            } else {
                short hi = f2bs(v);
                ((short*)O0)[oi] = hi;
                ((short*)O1)[oi] = f2bs(v - bs2f(hi));
            }
        }
    }
}

// batched-direction generic GEMM
struct GDir { const void* A0; const void* Al; const short* Wh; const short* Wl;
              const float* bias; void* O0; void* O1; };

template<int AM, int OM, int RELU, int BS>
__global__ __launch_bounds__(256) void gemm_k(GDir p0, GDir p1)
{
    GDir p = blockIdx.z ? p1 : p0;
    gemm_body<AM, OM, RELU, BS>(p.A0, p.Al, p.Wh, p.Wl, p.bias, p.O0, p.O1,
                                blockIdx.x * 64, blockIdx.y * 64);
}

// small dual GEMM (M=64): vW1 = v@mW1, vW2 = v@mW2+mb; fw direction only
// (bw's attn2gate never reads vW1/vW2: o0 == 0 there). grid (1, 8, 1).
struct G2Dir { const float* A; const short* W1h; const short* W1l;
               const short* W2h; const short* W2l; const float* b2;
               float* C1; float* C2; };

__global__ __launch_bounds__(256) void gemm2s_k(G2Dir p0)
{
    G2Dir p = p0;
    int y = blockIdx.y;
    const short* Wh = (y < 4) ? p.W1h : p.W2h;
    const short* Wl = (y < 4) ? p.W1l : p.W2l;
    void* C = (y < 4) ? (void*)p.C1 : (void*)p.C2;
    const float* bias = (y < 4) ? nullptr : p.b2;
    gemm_body<1, 0, 0, 0>(p.A, nullptr, Wh, Wl, bias, C, nullptr, 0, (y & 3) * 64);
}

// ---------- fused dual mSA-GEMM + level-1 masked attention, 512 threads ----------
// Grid (bn*2, dchunk, dir) = 1024 blocks. Sibling blocks (row-parity split)
// redundantly compute the full 64x64 P/Q tile (A-hi-only GEMM), then each runs
// the tail for 32 interleaved rows. Tail LDS: QX packed as bf16 pair in one
// word [d*65 + j] (bank = (d+j)%32, 2-way free) -> 33.5 KB total -> 4 blk/CU.
//   P' = exp(0.4A)*(-ln2/10); w = exp2(rcp(fma(P',q,-ln2/10))) = exp(-10/(1+u)).
struct MbloDir { const short* Ah;
                 const short* W1h; const short* W2h;
                 const float* mb; short* Hh; int fw; };

__global__ __launch_bounds__(512) void mblo_k(MbloDir p0, MbloDir p1)
{
    __shared__ char smraw[33536] __attribute__((aligned(16)));
    short* gAh  = (short*)smraw;            // 64*72 shorts each (GEMM phase)
    short* gB1h = gAh + 4608;
    short* gB2h = gAh + 9216;
    float* aP   = (float*)smraw;            // [i*66 + l] P' (tail overlay, 16.9 KB)
    unsigned int* aQX = (unsigned int*)(smraw + 16896); // [d*65 + j]: lo=Q bf16, hi=X bf16

    const float KLN = -0.06931471805599453f;   // -ln2/10

    MbloDir p = blockIdx.z ? p1 : p0;
    int tid = threadIdx.x;
    int w = tid >> 6, l = tid & 63;
    int m = l & 15, q = l >> 4;
    int rh = w >> 1;            // row strip 0..3
    int cb = (w & 1) * 2;       // col-frag base: 0 or 2
    int bn = blockIdx.x >> 1, ipar = blockIdx.x & 1;
    int row0 = bn * 64, d0 = blockIdx.y * 64;
    int srow = tid >> 3;        // staging row 0..63
    int skl  = (tid & 7) * 8;   // staging k offset

    f32x4 acc1[2], acc2[2];
    #pragma unroll
    for (int cf = 0; cf < 2; cf++) { acc1[cf] = (f32x4)(0.f); acc2[cf] = (f32x4)(0.f); }

    for (int kh = 0; kh < 4; kh++) {
        int kbase = kh * 64;
        size_t ga = (size_t)(row0 + srow) * 256 + kbase + skl;
        *(short8*)&gAh[srow * 72 + skl] = *(const short8*)(p.Ah + ga);
        size_t gb = (size_t)(d0 + srow) * 256 + kbase + skl;
        *(short8*)&gB1h[srow * 72 + skl] = *(const short8*)(p.W1h + gb);
        *(short8*)&gB2h[srow * 72 + skl] = *(const short8*)(p.W2h + gb);
        __syncthreads();
        #pragma unroll
        for (int ch = 0; ch < 2; ch++) {
            int k = ch * 32 + q * 8;
            short8 ah = *(const short8*)&gAh[(rh * 16 + m) * 72 + k];
            #pragma unroll
            for (int cf = 0; cf < 2; cf++) {
                int bofs = ((cb + cf) * 16 + m) * 72 + k;
                short8 b1 = *(const short8*)&gB1h[bofs];
                acc1[cf] = MFMA_B16(ah, b1, acc1[cf]);
                short8 b2 = *(const short8*)&gB2h[bofs];
                acc2[cf] = MFMA_B16(ah, b2, acc2[cf]);
            }
        }
        __syncthreads();   // also guards the union overwrite below
    }
    // epilogue: P' row-major f32; Q bf16 into low half of packed QX word
    short* sQX = (short*)aQX;
    #pragma unroll
    for (int cf = 0; cf < 2; cf++) {
        int col = (cb + cf) * 16 + m;        // d index
        float mbv = p.mb[d0 + col];
        #pragma unroll
        for (int r = 0; r < 4; r++) {
            int row = rh * 16 + q * 4 + r;   // j index
            aP[row * 66 + col] = __expf(0.4f * acc1[cf][r]) * KLN;
            sQX[col * 130 + 2 * row] = f2bs(__expf(0.4f * (acc2[cf][r] + mbv)));
        }
    }
    {   // X tile (bf16 hi plane, raw copy) into high halves
        size_t gx = (size_t)(row0 + srow) * 256 + d0 + skl;
        short8 xh = *(const short8*)(p.Ah + gx);
        #pragma unroll
        for (int t = 0; t < 8; t++)
            sQX[(skl + t) * 130 + 2 * srow + 1] = xh[t];
    }
    __syncthreads();
    // masked attention, exact bounds: wave w handles rows {ipar + 2*(w + 8t)}, t<4
    const unsigned int* lane_qx = &aQX[l * 65];
    #pragma unroll
    for (int t8 = 0; t8 < 4; t8++) {
        int i = ipar + 2 * (w + 8 * t8);
        float Pp = aP[i * 66 + l];
        int js = p.fw ? (i + 1) : 0;
        int je = p.fw ? 64 : i;
        float den0 = 0.f, den1 = 0.f, num0 = 0.f, num1 = 0.f;
        int j = js;
        for (; j + 4 <= je; j += 4) {
            unsigned int u0 = lane_qx[j];
            unsigned int u1 = lane_qx[j + 1];
            unsigned int u2 = lane_qx[j + 2];
            unsigned int u3 = lane_qx[j + 3];
            float q0 = bs2f((short)(u0 & 0xffff)), x0 = bs2f((short)(u0 >> 16));
            float q1 = bs2f((short)(u1 & 0xffff)), x1 = bs2f((short)(u1 >> 16));
            float q2 = bs2f((short)(u2 & 0xffff)), x2 = bs2f((short)(u2 >> 16));
            float q3 = bs2f((short)(u3 & 0xffff)), x3 = bs2f((short)(u3 >> 16));
            float w0 = EXP2F(__builtin_amdgcn_rcpf(fmaf(Pp, q0, KLN)));
            float w1 = EXP2F(__builtin_amdgcn_rcpf(fmaf(Pp, q1, KLN)));
            float w2 = EXP2F(__builtin_amdgcn_rcpf(fmaf(Pp, q2, KLN)));
            float w3 = EXP2F(__builtin_amdgcn_rcpf(fmaf(Pp, q3, KLN)));
            den0 += w0; num0 = fmaf(w0, x0, num0);
            den1 += w1; num1 = fmaf(w1, x1, num1);
            den0 += w2; num0 = fmaf(w2, x2, num0);
            den1 += w3; num1 = fmaf(w3, x3, num1);
        }
        for (; j < je; j++) {
            unsigned int u0 = lane_qx[j];
            float q0 = bs2f((short)(u0 & 0xffff)), x0 = bs2f((short)(u0 >> 16));
            float wgt = EXP2F(__builtin_amdgcn_rcpf(fmaf(Pp, q0, KLN)));
            den0 += wgt; num0 = fmaf(wgt, x0, num0);
        }
        float den = den0 + den1, num = num0 + num1;
        bool valid = p.fw ? (i < 63) : (i > 0);
        float out = valid ? (num * __builtin_amdgcn_rcpf(den)) : 0.f;
        p.Hh[(size_t)(row0 + i) * 256 + d0 + l] = f2bs(out);
    }
}

// ---------- fused s2t logits GEMM (single-plane W) + softmax pool ----------
struct PoolDir { const short* T1; const short* Wh; const float* bias;
                 const short* Hh; float* V; };

__global__ __launch_bounds__(256) void s2t_pool_k(PoolDir p0, PoolDir p1)
{
    __shared__ char smraw[37888] __attribute__((aligned(16)));
    short* gAh = (short*)smraw;             // 64*72
    short* gBh = gAh + 4608;
    float* aL = (float*)smraw;              // 64*68
    float* aH = aL + 4352;
    float* rm = aL + 8704;                  // 4*64
    float* rd = aL + 8960;
    float* rn = aL + 9216;

    PoolDir p = blockIdx.z ? p1 : p0;
    int tid = threadIdx.x;
    int w = tid >> 6, l = tid & 63;
    int m = l & 15, q = l >> 4;
    int sr = w * 16 + m;
    int row0 = blockIdx.x * 64, d0 = blockIdx.y * 64;

    f32x4 acc[4];
    #pragma unroll
    for (int cf = 0; cf < 4; cf++) acc[cf] = (f32x4)(0.f);

    for (int kh = 0; kh < 4; kh++) {
        int kbase = kh * 64;
        #pragma unroll
        for (int i = 0; i < 2; i++) {
            int kl = q * 8 + 32 * i;
            *(short8*)&gAh[sr * 72 + kl] =
                *(const short8*)(p.T1 + (size_t)(row0 + sr) * 256 + kbase + kl);
            *(short8*)&gBh[sr * 72 + kl] =
                *(const short8*)(p.Wh + (size_t)(d0 + sr) * 256 + kbase + kl);
        }
        __syncthreads();
        #pragma unroll
        for (int ch = 0; ch < 2; ch++) {
            int k = ch * 32 + q * 8;
            short8 ah = *(const short8*)&gAh[(w * 16 + m) * 72 + k];
            #pragma unroll
            for (int cf = 0; cf < 4; cf++) {
                short8 bh = *(const short8*)&gBh[(cf * 16 + m) * 72 + k];
                acc[cf] = MFMA_B16(ah, bh, acc[cf]);
            }
        }
        __syncthreads();
    }
    #pragma unroll
    for (int cf = 0; cf < 4; cf++) {
        int col = cf * 16 + m;
        float bv = p.bias[d0 + col];
        #pragma unroll
        for (int r = 0; r < 4; r++) {
            int row = w * 16 + q * 4 + r;
            aL[row * 68 + col] = acc[cf][r] + bv;
        }
    }
    #pragma unroll
    for (int it = 0; it < 2; it++) {
        int e = tid + it * 256;
        int j = e >> 3, d8 = (e & 7) * 8;
        short8 xh = *(const short8*)(p.Hh + (size_t)(row0 + j) * 256 + d0 + d8);
        #pragma unroll
        for (int t = 0; t < 8; t++)
            aH[j * 68 + d8 + t] = bs2f(xh[t]);
    }
    __syncthreads();
    int dl = tid & 63, rq = tid >> 6;
    float mx = -1e30f, den = 0.f, num = 0.f;
    #pragma unroll
    for (int rr = 0; rr < 16; rr++) {
        int r = rq * 16 + rr;
        float lv = aL[r * 68 + dl];
        float hv = aH[r * 68 + dl];
        if (lv > mx) {
            float sc = __expf(mx - lv);
            den *= sc; num *= sc; mx = lv;
        }
        float wgt = __expf(lv - mx);
        den += wgt; num += wgt * hv;
    }
    rm[rq * 64 + dl] = mx; rd[rq * 64 + dl] = den; rn[rq * 64 + dl] = num;
    __syncthreads();
    if (rq == 0) {
        float M = fmaxf(fmaxf(rm[dl], rm[64 + dl]), fmaxf(rm[128 + dl], rm[192 + dl]));
        float D = 0.f, Nn = 0.f;
        #pragma unroll
        for (int k = 0; k < 4; k++) {
            float sc = __expf(rm[k * 64 + dl] - M);
            D += rd[k * 64 + dl] * sc;
            Nn += rn[k * 64 + dl] * sc;
        }
        p.V[(size_t)blockIdx.x * 256 + d0 + dl] = Nn / D;
    }
}

// ---------- fused level-2 attention (row 0) + gate ----------
struct GateDir { const float* vW1; const float* vW2; const float* V;
                 const float* gW1; const float* gW2; const float* gb;
                 float* E0; int fw; };

__global__ __launch_bounds__(256) void attn2gate_k(GateDir p0, GateDir p1)
{
    GateDir p = blockIdx.z ? p1 : p0;
    __shared__ float so[256], sv[256], red[4][64];
    int b = blockIdx.x, k = threadIdx.x;
    float o = 0.f;
    if (p.fw) {
        float qv = p.vW1[(size_t)(b * 16) * 256 + k];
        float den = 0.f, num = 0.f;
        for (int j = 1; j < 16; j++) {
            float z = (qv + p.vW2[(size_t)(b * 16 + j) * 256 + k]) * 0.2f;
            float e2 = __expf(2.f * z);
            float t = 1.f - 2.f / (e2 + 1.f);
            float wgt = __expf(5.f * t);
            den += wgt; num += wgt * p.V[(size_t)(b * 16 + j) * 256 + k];
        }
        o = num / den;
    }
    so[k] = o;
    sv[k] = p.V[(size_t)(b * 16) * 256 + k];
    __syncthreads();
    int c = k & 63, ks = k >> 6;
    int gc = blockIdx.y * 64 + c;
    float acc = 0.f;
    int k0 = ks * 64;
    #pragma unroll 8
    for (int kk = 0; kk < 64; kk++) {
        int kx = k0 + kk;
        acc += so[kx] * p.gW1[(size_t)kx * 256 + gc] + sv[kx] * p.gW2[(size_t)kx * 256 + gc];
    }
    red[ks][c] = acc;
    __syncthreads();
    if (ks == 0) {
        float a = red[0][c] + red[1][c] + red[2][c] + red[3][c] + p.gb[gc];
        float G = 1.f / (1.f + __expf(-a));
        p.E0[b * 256 + gc] = G * so[gc] + (1.f - G) * sv[gc];
    }
}

// ---------- fusion: grid (64 bt, 4 dchunk, 2 dir), split-K(4x192) x 64-col ----------
struct FuseDir { const short* INh; const short* Hh;
                 const float* E0; const float* fW1; const float* fb1;
                 const float* fW2; const float* fb2; };

__global__ __launch_bounds__(256) void fusion_k(FuseDir p0, FuseDir p1, float* __restrict__ out)
{
    FuseDir p = blockIdx.z ? p1 : p0;
    __shared__ float cat[768];
    __shared__ float red1[4][64], red2[4][64];
    int bt = blockIdx.x, b = bt >> 4, t = bt & 15;
    int c = threadIdx.x & 63, ks = threadIdx.x >> 6;
    int gc = blockIdx.y * 64 + c;
    size_t xrow = ((size_t)b * 1024 + t) * 256;   // (b, n=0, r=t)
    cat[threadIdx.x]       = bs2f(p.INh[xrow + threadIdx.x]);
    cat[256 + threadIdx.x] = bs2f(p.Hh[xrow + threadIdx.x]);
    cat[512 + threadIdx.x] = p.E0[b * 256 + threadIdx.x];
    __syncthreads();
    float a1 = 0.f, a2 = 0.f;
    int k0 = ks * 192;
    #pragma unroll 8
    for (int kk = 0; kk < 192; kk++) {
        int k = k0 + kk;
        float cv = cat[k];
        a1 += cv * p.fW1[(size_t)k * 256 + gc];
        a2 += cv * p.fW2[(size_t)k * 256 + gc];
    }
    red1[ks][c] = a1; red2[ks][c] = a2;
    __syncthreads();
    if (ks == 0) {
        float s1 = red1[0][c] + red1[1][c] + red1[2][c] + red1[3][c] + p.fb1[gc];
        float s2 = red2[0][c] + red2[1][c] + red2[2][c] + red2[3][c] + p.fb2[gc];
        float fus = fmaxf(s1, 0.f);
        float Gf = 1.f / (1.f + __expf(-s2));
        float u = Gf * fus + (1.f - Gf) * cat[gc];
        out[((size_t)(b * 16 + t)) * 512 + (size_t)blockIdx.z * 256 + gc] = u;
    }
}

extern "C" void kernel_launch(void* const* d_in, const int* in_sizes, int n_in,
                              void* d_out, int out_size, void* d_ws, size_t ws_size,
                              hipStream_t stream)
{
    const float* x = (const float*)d_in[0];
    char* base = (char*)d_ws;
    auto alloc = [&](size_t bytes){ void* r = base; base += (bytes + 255) & ~255ULL; return r; };
    short* inH = (short*)alloc(2 * 1048576 * 2);
    short* hH  = (short*)alloc(2 * 1048576 * 2);
    short* t1  = (short*)alloc(2 * 1048576 * 2);
    short* wtH = (short*)alloc(10 * 65536 * 2);
    short* wtL = (short*)alloc(10 * 65536 * 2);
    float* v   = (float*)alloc(2 * 16384 * 4);
    float* vW1 = (float*)alloc(16384 * 4);
    float* vW2 = (float*)alloc(16384 * 4);
    float* E0  = (float*)alloc(2 * 1024 * 4);

    SrcPack sp;
    const int src_idx[5] = {0, 2, 3, 5, 7};  // fcW, mW1, mW2, s2tW1, s2tW
    for (int p = 0; p < 2; p++)
        for (int i = 0; i < 5; i++)
            sp.s[p * 5 + i] = (const float*)d_in[1 + p * 16 + src_idx[i]];
    prep_k<<<dim3(16, 10), 256, 0, stream>>>(sp, wtH, wtL);

    GDir fc[2], s2t1[2];
    MbloDir mbd[2];
    PoolDir pld[2];
    G2Dir g2d;
    GateDir gtd[2];
    FuseDir fsd[2];
    for (int p = 0; p < 2; p++) {
        int bi = 1 + p * 16;
        const float* fcb   = (const float*)d_in[bi + 1];
        const float* mb    = (const float*)d_in[bi + 4];
        const float* s2tb1 = (const float*)d_in[bi + 6];
        const float* s2tb  = (const float*)d_in[bi + 8];
        size_t po = (size_t)p * 1048576;
        const short* W0h = wtH + (size_t)(p * 5 + 0) * 65536, *W0l = wtL + (size_t)(p * 5 + 0) * 65536;
        const short* W1h = wtH + (size_t)(p * 5 + 1) * 65536, *W1l = wtL + (size_t)(p * 5 + 1) * 65536;
        const short* W2h = wtH + (size_t)(p * 5 + 2) * 65536, *W2l = wtL + (size_t)(p * 5 + 2) * 65536;
        const short* W3h = wtH + (size_t)(p * 5 + 3) * 65536;
        const short* W4h = wtH + (size_t)(p * 5 + 4) * 65536;

        fc[p]   = { x, nullptr, W0h, W0l, fcb, inH + po, nullptr };
        mbd[p]  = { inH + po, W1h, W2h, mb, hH + po, (p == 0) };
        s2t1[p] = { hH + po, nullptr, W3h, nullptr, s2tb1, t1 + po, nullptr };
        pld[p]  = { t1 + po, W4h, s2tb, hH + po, v + p * 16384 };
        if (p == 0) g2d = { v, W1h, W1l, W2h, W2l, mb, vW1, vW2 };
        gtd[p]  = { vW1, vW2, v + p * 16384,
                    (const float*)d_in[bi + 9], (const float*)d_in[bi + 10],
                    (const float*)d_in[bi + 11], E0 + p * 1024, (p == 0) };
        fsd[p]  = { inH + po, hH + po, E0 + p * 1024,
                    (const float*)d_in[bi + 12], (const float*)d_in[bi + 13],
                    (const float*)d_in[bi + 14], (const float*)d_in[bi + 15] };
    }

    gemm_k<1, 1, 1, 0><<<dim3(64, 4, 2), 256, 0, stream>>>(fc[0], fc[1]);
    mblo_k<<<dim3(128, 4, 2), 512, 0, stream>>>(mbd[0], mbd[1]);
    gemm_k<0, 1, 1, 1><<<dim3(64, 4, 2), 256, 0, stream>>>(s2t1[0], s2t1[1]);
    s2t_pool_k<<<dim3(64, 4, 2), 256, 0, stream>>>(pld[0], pld[1]);
    gemm2s_k<<<dim3(1, 8, 1), 256, 0, stream>>>(g2d);      // fw only: bw never reads vW1/vW2
    attn2gate_k<<<dim3(4, 4, 2), 256, 0, stream>>>(gtd[0], gtd[1]);
    fusion_k<<<dim3(64, 4, 2), 256, 0, stream>>>(fsd[0], fsd[1], (float*)d_out);
}